// Round 1
// baseline (843.434 us; speedup 1.0000x reference)
//
#include <hip/hip_runtime.h>

typedef unsigned short u16;
typedef unsigned int u32;
typedef __attribute__((ext_vector_type(8))) short bf16x8;
typedef __attribute__((ext_vector_type(4))) float f32x4;
typedef __attribute__((ext_vector_type(16))) float f32x16;

__device__ __forceinline__ u16 f2bf(float f) {
  u32 u = __float_as_uint(f);
  return (u16)((u + 0x7fffu + ((u >> 16) & 1u)) >> 16);
}
__device__ __forceinline__ float bf2f(u16 h) {
  return __uint_as_float(((u32)h) << 16);
}

__device__ __forceinline__ void glds16(const void* g, void* l) {
  __builtin_amdgcn_global_load_lds(
      (const __attribute__((address_space(1))) unsigned int*)g,
      (__attribute__((address_space(3))) unsigned int*)l, 16, 0, 0);
}

// unpack 16 bf16 -> 16 f32 (two 16-B loads)
__device__ __forceinline__ f32x16 unpack16(const u16* p) {
  uint4 a = *(const uint4*)p, b = *(const uint4*)(p + 8);
  f32x16 r;
  r[0]  = __uint_as_float(a.x << 16); r[1]  = __uint_as_float(a.x & 0xffff0000u);
  r[2]  = __uint_as_float(a.y << 16); r[3]  = __uint_as_float(a.y & 0xffff0000u);
  r[4]  = __uint_as_float(a.z << 16); r[5]  = __uint_as_float(a.z & 0xffff0000u);
  r[6]  = __uint_as_float(a.w << 16); r[7]  = __uint_as_float(a.w & 0xffff0000u);
  r[8]  = __uint_as_float(b.x << 16); r[9]  = __uint_as_float(b.x & 0xffff0000u);
  r[10] = __uint_as_float(b.y << 16); r[11] = __uint_as_float(b.y & 0xffff0000u);
  r[12] = __uint_as_float(b.z << 16); r[13] = __uint_as_float(b.z & 0xffff0000u);
  r[14] = __uint_as_float(b.w << 16); r[15] = __uint_as_float(b.w & 0xffff0000u);
  return r;
}

// ---------------------------------------------------------------------------
// convert edge f32 [131072][256] -> bf16 tiled+swizzled [1024 rt][4 kc][128 r][64 k]
// ---------------------------------------------------------------------------
__global__ __launch_bounds__(256) void convert_edge(
    const float* __restrict__ src, u16* __restrict__ dst) {
  int g = blockIdx.x * 256 + threadIdx.x;
  int kg = g & 7, r = (g >> 3) & 127, kc = (g >> 10) & 3, rt = g >> 12;
  const float* s = src + ((long)(rt * 128 + r) * 256 + kc * 64 + kg * 8);
  float4 a = *(const float4*)s, b = *(const float4*)(s + 4);
  ushort4 lo, hi;
  lo.x = f2bf(a.x); lo.y = f2bf(a.y); lo.z = f2bf(a.z); lo.w = f2bf(a.w);
  hi.x = f2bf(b.x); hi.y = f2bf(b.y); hi.z = f2bf(b.z); hi.w = f2bf(b.w);
  u16* d = dst + (long)rt * 65536 + kc * 16384 + r * 64 + (kg ^ (r & 7)) * 8;
  *(ushort4*)d = lo;
  *(ushort4*)(d + 4) = hi;
}

// ---------------------------------------------------------------------------
// Edge GEMM: E[131072 x 512] = A_tiled(bf16) * Bt_tiled(bf16)^T, K=256.
// ---------------------------------------------------------------------------
__global__ __launch_bounds__(256) void gemm_edge(
    const u16* __restrict__ A, const u16* __restrict__ Bt,
    u16* __restrict__ E) {
  __shared__ __align__(16) u16 Asm[8192];
  __shared__ __align__(16) u16 Bsm[8192];
  const int tid = threadIdx.x, lane = tid & 63, w = tid >> 6;
  const int m = lane & 15, q = lane >> 4;
  const int rt = blockIdx.x >> 2, ct = blockIdx.x & 3;
  const int wrow = (w & 1) * 64, wcol = (w >> 1) * 64;
  const char* Ab = (const char*)A + (long)rt * 131072;
  const char* Bb = (const char*)Bt + (long)ct * 65536;
  f32x4 acc[4][4];
#pragma unroll
  for (int r = 0; r < 4; ++r)
#pragma unroll
    for (int c = 0; c < 4; ++c) acc[r][c] = (f32x4){0.f, 0.f, 0.f, 0.f};

  for (int kc = 0; kc < 4; ++kc) {
#pragma unroll
    for (int t = 0; t < 4; ++t) {
      glds16(Ab + kc * 32768 + t * 4096 + tid * 16,
             (char*)Asm + t * 4096 + tid * 16);
      glds16(Bb + kc * 16384 + t * 4096 + tid * 16,
             (char*)Bsm + t * 4096 + tid * 16);
    }
    __syncthreads();
#pragma unroll
    for (int s = 0; s < 2; ++s) {
      const int ko2 = (s * 32 + q * 8) * 2;
      bf16x8 av[4], bv[4];
#pragma unroll
      for (int r = 0; r < 4; ++r) {
        int row = wrow + r * 16 + m;
        av[r] = *(const bf16x8*)((const char*)Asm + row * 128 +
                                 (ko2 ^ ((row & 7) * 16)));
      }
#pragma unroll
      for (int c = 0; c < 4; ++c) {
        int col = wcol + c * 16 + m;
        bv[c] = *(const bf16x8*)((const char*)Bsm + col * 128 +
                                 (ko2 ^ ((col & 7) * 16)));
      }
#pragma unroll
      for (int r = 0; r < 4; ++r)
#pragma unroll
        for (int c = 0; c < 4; ++c)
          acc[r][c] = __builtin_amdgcn_mfma_f32_16x16x32_bf16(
              av[r], bv[c], acc[r][c], 0, 0, 0);
    }
    __syncthreads();
  }
#pragma unroll
  for (int r = 0; r < 4; ++r)
#pragma unroll
    for (int c = 0; c < 4; ++c)
#pragma unroll
      for (int g = 0; g < 4; ++g) {
        long gr = (long)rt * 128 + wrow + r * 16 + q * 4 + g;
        int gc = ct * 128 + wcol + c * 16 + m;
        E[gr * 512 + gc] = f2bf(acc[r][c][g]);
      }
}

// ---------------------------------------------------------------------------
// Generic small GEMM (f32 A): C[M x Ntot] = A[M x K] * Bt[Ntot x K]^T
// RF*16-row x 256-col tile, 4 waves (each RF*16 x 64).
// RELU0: also write relu(v) to relu_dst[gr*256+gc] for gc<256 (T0 fusion).
// ---------------------------------------------------------------------------
template<int K, int RF, bool OUT_BF16, bool RELU0>
__global__ __launch_bounds__(256) void gemm_mfma(
    const float* __restrict__ A, const u16* __restrict__ Bt,
    void* __restrict__ Cv, int Ntot, float* __restrict__ relu_dst) {
  constexpr int ROWS = RF * 16;
  constexpr int LD = 72;
  __shared__ __align__(16) u16 Asm[ROWS * LD];
  __shared__ __align__(16) u16 Bsm[256 * LD];
  const int tid = threadIdx.x;
  const int lane = tid & 63;
  const int w = tid >> 6;
  const int m = lane & 15;
  const int q = lane >> 4;
  const int wcol = w * 64;
  const long rowbase = (long)blockIdx.x * ROWS;
  const long colbase = (long)blockIdx.y * 256;
  f32x4 acc[RF][4];
#pragma unroll
  for (int r = 0; r < RF; ++r)
#pragma unroll
    for (int c = 0; c < 4; ++c) acc[r][c] = (f32x4){0.f, 0.f, 0.f, 0.f};

  for (int kc = 0; kc < K / 64; ++kc) {
    const int kb = kc * 64;
#pragma unroll
    for (int it = 0; it < RF; ++it) {
      int f = it * 256 + tid;
      int r = f >> 4, c4 = (f & 15) * 4;
      float4 v = *(const float4*)(A + (rowbase + r) * K + kb + c4);
      ushort4 h;
      h.x = f2bf(v.x); h.y = f2bf(v.y); h.z = f2bf(v.z); h.w = f2bf(v.w);
      *(ushort4*)&Asm[r * LD + c4] = h;
    }
#pragma unroll
    for (int it = 0; it < 8; ++it) {
      int f = it * 256 + tid;
      int c = f >> 3, k8 = (f & 7) * 8;
      *(uint4*)&Bsm[c * LD + k8] =
          *(const uint4*)(Bt + (colbase + c) * K + kb + k8);
    }
    __syncthreads();
#pragma unroll
    for (int s = 0; s < 2; ++s) {
      const int ko = s * 32 + q * 8;
      bf16x8 av[RF], bv[4];
#pragma unroll
      for (int r = 0; r < RF; ++r)
        av[r] = *(const bf16x8*)&Asm[(r * 16 + m) * LD + ko];
#pragma unroll
      for (int c = 0; c < 4; ++c)
        bv[c] = *(const bf16x8*)&Bsm[(wcol + c * 16 + m) * LD + ko];
#pragma unroll
      for (int r = 0; r < RF; ++r)
#pragma unroll
        for (int c = 0; c < 4; ++c)
          acc[r][c] = __builtin_amdgcn_mfma_f32_16x16x32_bf16(
              av[r], bv[c], acc[r][c], 0, 0, 0);
    }
    __syncthreads();
  }
#pragma unroll
  for (int r = 0; r < RF; ++r)
#pragma unroll
    for (int c = 0; c < 4; ++c)
#pragma unroll
      for (int g = 0; g < 4; ++g) {
        long gr = rowbase + r * 16 + q * 4 + g;
        long gc = colbase + wcol + c * 16 + m;
        float v = acc[r][c][g];
        if (OUT_BF16) ((u16*)Cv)[gr * Ntot + gc] = f2bf(v);
        else          ((float*)Cv)[gr * Ntot + gc] = v;
        if (RELU0) {
          if (gc < 256) relu_dst[gr * 256 + gc] = fmaxf(v, 0.f);
        }
      }
}

// ---------------------------------------------------------------------------
// Weight tables (unchanged).
// ---------------------------------------------------------------------------
__global__ __launch_bounds__(256) void prep_bt(
    const float* __restrict__ weight, const float* __restrict__ align_lin,
    const float* __restrict__ fuse1_w, const float* __restrict__ fuse2_w,
    const float* __restrict__ fc1_w0, const float* __restrict__ fc2_w0,
    const float* __restrict__ fc3_w,
    u16* BtE1, u16* BtE2, u16* BtW0, u16* BtLoop, u16* BtFc3) {
  int g = blockIdx.x * 256 + threadIdx.x;  // 0..917503
  if (g < 262144) {
    int t = g & 131071;
    int col = t >> 8, k = t & 255;
    float v;
    if (g < 131072)
      v = (col < 256) ? fuse1_w[(256 + k) * 256 + col]
                      : fc1_w0[(512 + k) * 256 + (col - 256)];
    else
      v = (col < 256) ? fuse2_w[(256 + k) * 256 + col]
                      : fc2_w0[(512 + k) * 256 + (col - 256)];
    int ct = col >> 7, cc = col & 127, kc = k >> 6, kk = k & 63;
    u16* dst = (g < 131072) ? BtE1 : BtE2;
    dst[ct * 32768 + kc * 8192 + cc * 64 + (kk ^ ((cc & 7) * 8))] = f2bf(v);
  } else if (g < 393216) {
    int t = g - 262144;
    int c = t >> 8, k = t & 255;
    float v = (c < 256) ? weight[k * 256 + c] : align_lin[k * 256 + (c - 256)];
    BtW0[t] = f2bf(v);
  } else if (g < 786432) {
    int t = g - 393216;
    int c = t >> 8, k = t & 255;
    int seg = c >> 8, cc = c & 255;
    float v;
    if      (seg == 0) v = fuse1_w[k * 256 + cc];
    else if (seg == 1) v = fuse2_w[k * 256 + cc];
    else if (seg == 2) v = fc1_w0[k * 256 + cc];
    else if (seg == 3) v = fc1_w0[(256 + k) * 256 + cc];
    else if (seg == 4) v = fc2_w0[k * 256 + cc];
    else               v = fc2_w0[(256 + k) * 256 + cc];
    BtLoop[t] = f2bf(v);
  } else {
    int t = g - 786432;
    int c = t >> 9, k = t & 511;
    BtFc3[t] = f2bf(fc3_w[k * 256 + c]);
  }
}

// ---------------------------------------------------------------------------
// SelfAlignment (unchanged)
// ---------------------------------------------------------------------------
__global__ __launch_bounds__(128) void align_kernel(
    const float* __restrict__ text, const float* __restrict__ T0,
    const float* __restrict__ textmask, const float* __restrict__ align_bias,
    float* __restrict__ outss) {
  const int bi = blockIdx.x;
  const int b = bi >> 7;
  const int tid = threadIdx.x;
  __shared__ float ta[256];
  __shared__ float pr[128];
  __shared__ float red[128];
  ta[tid]       = T0[(long)bi * 512 + 256 + tid];
  ta[tid + 128] = T0[(long)bi * 512 + 384 + tid];
  __syncthreads();
  const float* trow = text + (long)(b * 128 + tid) * 256;
  float dot = 0.f;
  for (int d = 0; d < 256; d += 4) {
    float4 t4 = *(const float4*)(trow + d);
    dot += t4.x * ta[d] + t4.y * ta[d + 1] + t4.z * ta[d + 2] + t4.w * ta[d + 3];
  }
  float logit = dot + (1.0f - textmask[b * 128 + tid]) * -1e20f;
  pr[tid] = logit;
  red[tid] = logit;
  __syncthreads();
  for (int off = 64; off; off >>= 1) {
    if (tid < off) red[tid] = fmaxf(red[tid], red[tid + off]);
    __syncthreads();
  }
  float mx = red[0];
  __syncthreads();
  float e = __expf(pr[tid] - mx);
  red[tid] = e;
  __syncthreads();
  for (int off = 64; off; off >>= 1) {
    if (tid < off) red[tid] += red[tid + off];
    __syncthreads();
  }
  float inv = 1.0f / red[0];
  __syncthreads();
  pr[tid] = e * inv;
  __syncthreads();
  const float mi = textmask[bi];
  for (int h = 0; h < 2; ++h) {
    int d = tid + h * 128;
    float s = 0.f;
    for (int j = 0; j < 128; ++j)
      s += pr[j] * text[(long)(b * 128 + j) * 256 + d];
    outss[(long)bi * 256 + d] = s * mi + align_bias[d];
  }
}

// ---------------------------------------------------------------------------
// Fused gate/aggregate v2: two-phase per (b,i). 256 thr = 4 waves.
// Phase A: gate scalars s1[j], s2[j] for all 128 j  -> LDS (reads e_cf halves).
// Phase B: dependency-free stream acc += s[j]*relu(of+e_ff).
// Reduction: shfl across g16 groups, then 4x256 LDS partials (9.3 KB total).
// ---------------------------------------------------------------------------
__global__ __launch_bounds__(256) void fused_gate(
    const u16* __restrict__ E1, const u16* __restrict__ E2,
    const float* __restrict__ P, const float* __restrict__ adj1,
    const float* __restrict__ adj2, const float* __restrict__ fc1w1,
    const float* __restrict__ fc1b1, const float* __restrict__ fc2w1,
    const float* __restrict__ fc2b1, float* __restrict__ OU12) {
  const int tid = threadIdx.x, lane = tid & 63, w = tid >> 6;
  const int g16 = lane >> 4, l16 = lane & 15;
  const int bi = blockIdx.x, b = bi >> 7;
  const int db = l16 * 16;
  const long rowi = (long)bi * 1536;
  const long ebase = (long)bi * 65536;  // (b*16384 + i*128) * 512
  const int abase = bi * 128;

  __shared__ float sA[128], sB[128];
  __shared__ float redA[4][256], redB[4][256];
  __shared__ float dInv[2];

  // denominators: waves 0/1 reduce adj rows (128 values each)
  if (w < 2) {
    const float* adj = w ? adj2 : adj1;
    float v = adj[abase + lane] + adj[abase + 64 + lane];
#pragma unroll
    for (int off = 32; off; off >>= 1) v += __shfl_xor(v, off);
    if (lane == 0) dInv[w] = 1.f / (1.f + v);
  }

  // ---- Phase A: gate scalars ----
  {
    const f32x16 w1v = *(const f32x16*)(fc1w1 + db);
    const f32x16 w2v = *(const f32x16*)(fc2w1 + db);
    const f32x16 ti1 = *(const f32x16*)(P + rowi + 512 + db);
    const f32x16 ti2 = *(const f32x16*)(P + rowi + 1024 + db);
    const float b1 = fc1b1[0], b2 = fc2b1[0];
#pragma unroll
    for (int t = 0; t < 8; ++t) {
      const int j = w * 32 + t * 4 + g16;
      const long er = ebase + (long)j * 512;
      const long rowj = (long)((b << 7) + j) * 1536;
      f32x16 e1 = unpack16(E1 + er + 256 + db);
      f32x16 e2 = unpack16(E2 + er + 256 + db);
      f32x16 t1 = *(const f32x16*)(P + rowj + 768 + db);
      f32x16 t2 = *(const f32x16*)(P + rowj + 1280 + db);
      float z1 = 0.f, z2 = 0.f;
#pragma unroll
      for (int dd = 0; dd < 16; ++dd) {
        z1 += fmaxf(ti1[dd] + t1[dd] + e1[dd], 0.f) * w1v[dd];
        z2 += fmaxf(ti2[dd] + t2[dd] + e2[dd], 0.f) * w2v[dd];
      }
#pragma unroll
      for (int off = 1; off < 16; off <<= 1) {
        z1 += __shfl_xor(z1, off);
        z2 += __shfl_xor(z2, off);
      }
      if (l16 == 0) {
        sA[j] = adj1[abase + j] / (1.f + __expf(-(z1 + b1)));
        sB[j] = adj2[abase + j] / (1.f + __expf(-(z2 + b2)));
      }
    }
  }
  __syncthreads();

  // ---- Phase B: aggregation (pure stream, no cross-lane in loop) ----
  f32x16 acc1, acc2;
#pragma unroll
  for (int dd = 0; dd < 16; ++dd) { acc1[dd] = 0.f; acc2[dd] = 0.f; }
#pragma unroll
  for (int t = 0; t < 8; ++t) {
    const int j = w * 32 + t * 4 + g16;
    const long er = ebase + (long)j * 512;
    const long rowj = (long)((b << 7) + j) * 1536;
    f32x16 e1 = unpack16(E1 + er + db);
    f32x16 e2 = unpack16(E2 + er + db);
    f32x16 o1 = *(const f32x16*)(P + rowj + db);
    f32x16 o2 = *(const f32x16*)(P + rowj + 256 + db);
    const float s1 = sA[j], s2 = sB[j];
#pragma unroll
    for (int dd = 0; dd < 16; ++dd) {
      acc1[dd] += s1 * fmaxf(o1[dd] + e1[dd], 0.f);
      acc2[dd] += s2 * fmaxf(o2[dd] + e2[dd], 0.f);
    }
  }

  // reduce across the 4 g16 groups within each wave
#pragma unroll
  for (int dd = 0; dd < 16; ++dd) {
    float a = acc1[dd], c = acc2[dd];
    a += __shfl_xor(a, 16); a += __shfl_xor(a, 32);
    c += __shfl_xor(c, 16); c += __shfl_xor(c, 32);
    acc1[dd] = a; acc2[dd] = c;
  }
  // each lane writes its g16-quarter of the wave's 256-float partial
  *(float4*)&redA[w][db + g16 * 4] =
      make_float4(acc1[g16 * 4], acc1[g16 * 4 + 1],
                  acc1[g16 * 4 + 2], acc1[g16 * 4 + 3]);
  *(float4*)&redB[w][db + g16 * 4] =
      make_float4(acc2[g16 * 4], acc2[g16 * 4 + 1],
                  acc2[g16 * 4 + 2], acc2[g16 * 4 + 3]);
  __syncthreads();
  float o1 = redA[0][tid] + redA[1][tid] + redA[2][tid] + redA[3][tid];
  float o2 = redB[0][tid] + redB[1][tid] + redB[2][tid] + redB[3][tid];
  OU12[(long)bi * 512 + tid] = o1 * dInv[0];
  OU12[(long)bi * 512 + 256 + tid] = o2 * dInv[1];
}

// ---------------------------------------------------------------------------
// out = layernorm(relu(Y) + prev + bias) * gamma + beta
// ---------------------------------------------------------------------------
__global__ __launch_bounds__(256) void ln_kernel(
    const float* __restrict__ Y, const float* __restrict__ prev,
    const float* __restrict__ bias, const float* __restrict__ gamma,
    const float* __restrict__ beta, float* __restrict__ dst) {
  const int row = blockIdx.x, tid = threadIdx.x, lane = tid & 63, w = tid >> 6;
  const long idx = (long)row * 256 + tid;
  float v = fmaxf(Y[idx], 0.f) + prev[idx] + bias[tid];
  float s = v;
#pragma unroll
  for (int off = 32; off; off >>= 1) s += __shfl_xor(s, off);
  __shared__ float wsA[4], wsB[4];
  if (lane == 0) wsA[w] = s;
  __syncthreads();
  float mean = (wsA[0] + wsA[1] + wsA[2] + wsA[3]) * (1.0f / 256.0f);
  float c = v - mean;
  float s2 = c * c;
#pragma unroll
  for (int off = 32; off; off >>= 1) s2 += __shfl_xor(s2, off);
  if (lane == 0) wsB[w] = s2;
  __syncthreads();
  float var = (wsB[0] + wsB[1] + wsB[2] + wsB[3]) * (1.0f / 256.0f);
  dst[idx] = c * rsqrtf(var + 1e-5f) * gamma[tid] + beta[tid];
}

// ---------------------------------------------------------------------------
extern "C" void kernel_launch(void* const* d_in, const int* in_sizes, int n_in,
                              void* d_out, int out_size, void* d_ws, size_t ws_size,
                              hipStream_t stream) {
  const float* text      = (const float*)d_in[0];
  const float* adj1      = (const float*)d_in[1];
  const float* adj2      = (const float*)d_in[2];
  const float* edge1     = (const float*)d_in[3];
  const float* edge2     = (const float*)d_in[4];
  const float* textmask  = (const float*)d_in[5];
  const float* weight    = (const float*)d_in[6];
  const float* bias      = (const float*)d_in[7];
  const float* gamma     = (const float*)d_in[8];
  const float* beta      = (const float*)d_in[9];
  const float* fuse1_w   = (const float*)d_in[10];
  const float* fuse2_w   = (const float*)d_in[11];
  const float* fc3_w     = (const float*)d_in[12];
  const float* fc1_w0    = (const float*)d_in[13];
  const float* fc1_w1    = (const float*)d_in[14];
  const float* fc1_b1    = (const float*)d_in[15];
  const float* fc2_w0    = (const float*)d_in[16];
  const float* fc2_w1    = (const float*)d_in[17];
  const float* fc2_b1    = (const float*)d_in[18];
  const float* align_lin = (const float*)d_in[19];
  const float* align_bias= (const float*)d_in[20];
  float* outF = (float*)d_out;  // out: [0,262144), outss: [262144,524288)

  char* w8 = (char*)d_ws;
  u16* Ax   = (u16*)w8;                       // 64 MB (freed after edge GEMMs)
  u16* E1   = (u16*)(w8 + 67108864);          // 128 MB
  u16* E2   = (u16*)(w8 + 201326592);         // 128 MB
  u16* BtE1 = (u16*)(w8 + 335544320);
  u16* BtE2 = BtE1 + 131072;
  u16* BtW0 = BtE2 + 131072;
  u16* BtLoop = BtW0 + 131072;                // 1536 x 256
  u16* BtFc3  = BtLoop + 393216;              // 256 x 512
  // small f32 buffers live inside the Ax region (dead after edge GEMMs)
  float* P    = (float*)w8;                   // 1024 x 1536
  float* T0   = P + 1572864;                  // 1024 x 512
  float* OU12 = T0 + 524288;                  // 1024 x 512
  float* outb = OU12 + 524288;                // 1024 x 256
  float* Yb   = outb + 262144;                // 1024 x 256

  // 1) weight tables
  prep_bt<<<3584, 256, 0, stream>>>(weight, align_lin, fuse1_w, fuse2_w,
                                    fc1_w0, fc2_w0, fc3_w,
                                    BtE1, BtE2, BtW0, BtLoop, BtFc3);
  // 2) edge projections (loop-invariant): convert f32->bf16 tiled, then GEMM
  convert_edge<<<16384, 256, 0, stream>>>(edge1, Ax);
  gemm_edge<<<4096, 256, 0, stream>>>(Ax, BtE1, E1);
  convert_edge<<<16384, 256, 0, stream>>>(edge2, Ax);
  gemm_edge<<<4096, 256, 0, stream>>>(Ax, BtE2, E2);
  // 3) T0 = text @ [weight | align_lin], relu of first 256 cols fused -> outb
  gemm_mfma<256, 2, false, true><<<dim3(32, 2), 256, 0, stream>>>(
      text, BtW0, T0, 512, outb);
  // 4) self-alignment -> outss
  align_kernel<<<1024, 128, 0, stream>>>(text, T0, textmask, align_bias,
                                         outF + 262144);
  // 5) K = 3 GCN iterations
  for (int it = 0; it < 3; ++it) {
    gemm_mfma<256, 2, false, false><<<dim3(32, 6), 256, 0, stream>>>(
        outb, BtLoop, P, 1536, nullptr);
    fused_gate<<<1024, 256, 0, stream>>>(E1, E2, P, adj1, adj2, fc1_w1, fc1_b1,
                                         fc2_w1, fc2_b1, OU12);
    gemm_mfma<512, 2, false, false><<<dim3(32, 1), 256, 0, stream>>>(
        OU12, BtFc3, Yb, 256, nullptr);
    ln_kernel<<<1024, 256, 0, stream>>>(Yb, outb, bias, gamma, beta,
                                        (it == 2) ? outF : outb);
  }
}

// Round 2
// 739.670 us; speedup vs baseline: 1.1403x; 1.1403x over previous
//
#include <hip/hip_runtime.h>

typedef unsigned short u16;
typedef unsigned int u32;
typedef __attribute__((ext_vector_type(8))) short bf16x8;
typedef __attribute__((ext_vector_type(4))) float f32x4;

__device__ __forceinline__ u16 f2bf(float f) {
  u32 u = __float_as_uint(f);
  return (u16)((u + 0x7fffu + ((u >> 16) & 1u)) >> 16);
}

__device__ __forceinline__ void glds16(const void* g, void* l) {
  __builtin_amdgcn_global_load_lds(
      (const __attribute__((address_space(1))) unsigned int*)g,
      (__attribute__((address_space(3))) unsigned int*)l, 16, 0, 0);
}

// unpack 4 bf16 -> 4 f32 (one 8-B load)
__device__ __forceinline__ float4 unpack4(const u16* p) {
  uint2 a = *(const uint2*)p;
  float4 r;
  r.x = __uint_as_float(a.x << 16);
  r.y = __uint_as_float(a.x & 0xffff0000u);
  r.z = __uint_as_float(a.y << 16);
  r.w = __uint_as_float(a.y & 0xffff0000u);
  return r;
}

// ---------------------------------------------------------------------------
// Edge GEMM: E[131072 x 512] = edge(f32) @ Bt(bf16)^T, K=256.
// A staged from f32 with in-register bf16 convert into swizzled LDS
// (same layout the old convert_edge produced). XCD-grouped block mapping:
// the 4 ct-blocks of one rt land on one XCD -> A tile is L2-resident.
// ---------------------------------------------------------------------------
__global__ __launch_bounds__(256) void gemm_edge(
    const float* __restrict__ Af, const u16* __restrict__ Bt,
    u16* __restrict__ E) {
  __shared__ __align__(16) u16 Asm[8192];
  __shared__ __align__(16) u16 Bsm[8192];
  const int tid = threadIdx.x, lane = tid & 63, w = tid >> 6;
  const int m = lane & 15, q = lane >> 4;
  const int p = blockIdx.x;
  const int rt = (p & 7) * 128 + (p >> 5);  // XCD (p%8) owns rt block
  const int ct = (p >> 3) & 3;
  const int wrow = (w & 1) * 64, wcol = (w >> 1) * 64;
  const float* Ab = Af + (long)rt * 32768;  // 128 rows x 256 cols
  const char* Bb = (const char*)Bt + (long)ct * 65536;
  f32x4 acc[4][4];
#pragma unroll
  for (int r = 0; r < 4; ++r)
#pragma unroll
    for (int c = 0; c < 4; ++c) acc[r][c] = (f32x4){0.f, 0.f, 0.f, 0.f};

  for (int kc = 0; kc < 4; ++kc) {
    // A: 128 rows x 64 k f32 -> bf16, swizzled store
#pragma unroll
    for (int it = 0; it < 8; ++it) {
      int f = it * 256 + tid;
      int r = f >> 4, c4 = (f & 15) * 4;
      float4 v = *(const float4*)(Ab + (long)r * 256 + kc * 64 + c4);
      ushort4 h;
      h.x = f2bf(v.x); h.y = f2bf(v.y); h.z = f2bf(v.z); h.w = f2bf(v.w);
      *(ushort4*)((char*)Asm + r * 128 + ((c4 * 2) ^ ((r & 7) * 16))) = h;
    }
#pragma unroll
    for (int t = 0; t < 4; ++t)
      glds16(Bb + kc * 16384 + t * 4096 + tid * 16,
             (char*)Bsm + t * 4096 + tid * 16);
    __syncthreads();
#pragma unroll
    for (int s = 0; s < 2; ++s) {
      const int ko2 = (s * 32 + q * 8) * 2;
      bf16x8 av[4], bv[4];
#pragma unroll
      for (int r = 0; r < 4; ++r) {
        int row = wrow + r * 16 + m;
        av[r] = *(const bf16x8*)((const char*)Asm + row * 128 +
                                 (ko2 ^ ((row & 7) * 16)));
      }
#pragma unroll
      for (int c = 0; c < 4; ++c) {
        int col = wcol + c * 16 + m;
        bv[c] = *(const bf16x8*)((const char*)Bsm + col * 128 +
                                 (ko2 ^ ((col & 7) * 16)));
      }
#pragma unroll
      for (int r = 0; r < 4; ++r)
#pragma unroll
        for (int c = 0; c < 4; ++c)
          acc[r][c] = __builtin_amdgcn_mfma_f32_16x16x32_bf16(
              av[r], bv[c], acc[r][c], 0, 0, 0);
    }
    __syncthreads();
  }
#pragma unroll
  for (int r = 0; r < 4; ++r)
#pragma unroll
    for (int c = 0; c < 4; ++c)
#pragma unroll
      for (int g = 0; g < 4; ++g) {
        long gr = (long)rt * 128 + wrow + r * 16 + q * 4 + g;
        int gc = ct * 128 + wcol + c * 16 + m;
        E[gr * 512 + gc] = f2bf(acc[r][c][g]);
      }
}

// ---------------------------------------------------------------------------
// Generic small GEMM (f32 A): C[M x Ntot] = A[M x K] * Bt[Ntot x K]^T
// RF*16-row x 256-col tile, 4 waves. RELU0: fused relu of cols<256 -> relu_dst.
// SUM2: A_eff = A + A2 (elementwise, staged sum).
// ---------------------------------------------------------------------------
template<int K, int RF, bool OUT_BF16, bool RELU0, bool SUM2>
__global__ __launch_bounds__(256) void gemm_mfma(
    const float* __restrict__ A, const u16* __restrict__ Bt,
    void* __restrict__ Cv, int Ntot, float* __restrict__ relu_dst,
    const float* __restrict__ A2) {
  constexpr int ROWS = RF * 16;
  constexpr int LD = 72;
  __shared__ __align__(16) u16 Asm[ROWS * LD];
  __shared__ __align__(16) u16 Bsm[256 * LD];
  const int tid = threadIdx.x;
  const int lane = tid & 63;
  const int w = tid >> 6;
  const int m = lane & 15;
  const int q = lane >> 4;
  const int wcol = w * 64;
  const long rowbase = (long)blockIdx.x * ROWS;
  const long colbase = (long)blockIdx.y * 256;
  f32x4 acc[RF][4];
#pragma unroll
  for (int r = 0; r < RF; ++r)
#pragma unroll
    for (int c = 0; c < 4; ++c) acc[r][c] = (f32x4){0.f, 0.f, 0.f, 0.f};

  for (int kc = 0; kc < K / 64; ++kc) {
    const int kb = kc * 64;
#pragma unroll
    for (int it = 0; it < RF; ++it) {
      int f = it * 256 + tid;
      int r = f >> 4, c4 = (f & 15) * 4;
      float4 v = *(const float4*)(A + (rowbase + r) * K + kb + c4);
      if (SUM2) {
        float4 v2 = *(const float4*)(A2 + (rowbase + r) * K + kb + c4);
        v.x += v2.x; v.y += v2.y; v.z += v2.z; v.w += v2.w;
      }
      ushort4 h;
      h.x = f2bf(v.x); h.y = f2bf(v.y); h.z = f2bf(v.z); h.w = f2bf(v.w);
      *(ushort4*)&Asm[r * LD + c4] = h;
    }
#pragma unroll
    for (int it = 0; it < 8; ++it) {
      int f = it * 256 + tid;
      int c = f >> 3, k8 = (f & 7) * 8;
      *(uint4*)&Bsm[c * LD + k8] =
          *(const uint4*)(Bt + (colbase + c) * K + kb + k8);
    }
    __syncthreads();
#pragma unroll
    for (int s = 0; s < 2; ++s) {
      const int ko = s * 32 + q * 8;
      bf16x8 av[RF], bv[4];
#pragma unroll
      for (int r = 0; r < RF; ++r)
        av[r] = *(const bf16x8*)&Asm[(r * 16 + m) * LD + ko];
#pragma unroll
      for (int c = 0; c < 4; ++c)
        bv[c] = *(const bf16x8*)&Bsm[(wcol + c * 16 + m) * LD + ko];
#pragma unroll
      for (int r = 0; r < RF; ++r)
#pragma unroll
        for (int c = 0; c < 4; ++c)
          acc[r][c] = __builtin_amdgcn_mfma_f32_16x16x32_bf16(
              av[r], bv[c], acc[r][c], 0, 0, 0);
    }
    __syncthreads();
  }
#pragma unroll
  for (int r = 0; r < RF; ++r)
#pragma unroll
    for (int c = 0; c < 4; ++c)
#pragma unroll
      for (int g = 0; g < 4; ++g) {
        long gr = rowbase + r * 16 + q * 4 + g;
        long gc = colbase + wcol + c * 16 + m;
        float v = acc[r][c][g];
        if (OUT_BF16) ((u16*)Cv)[gr * Ntot + gc] = f2bf(v);
        else          ((float*)Cv)[gr * Ntot + gc] = v;
        if (RELU0) {
          if (gc < 256) relu_dst[gr * 256 + gc] = fmaxf(v, 0.f);
        }
      }
}

// ---------------------------------------------------------------------------
// Weight tables (unchanged).
// ---------------------------------------------------------------------------
__global__ __launch_bounds__(256) void prep_bt(
    const float* __restrict__ weight, const float* __restrict__ align_lin,
    const float* __restrict__ fuse1_w, const float* __restrict__ fuse2_w,
    const float* __restrict__ fc1_w0, const float* __restrict__ fc2_w0,
    const float* __restrict__ fc3_w,
    u16* BtE1, u16* BtE2, u16* BtW0, u16* BtLoop, u16* BtFc3) {
  int g = blockIdx.x * 256 + threadIdx.x;  // 0..917503
  if (g < 262144) {
    int t = g & 131071;
    int col = t >> 8, k = t & 255;
    float v;
    if (g < 131072)
      v = (col < 256) ? fuse1_w[(256 + k) * 256 + col]
                      : fc1_w0[(512 + k) * 256 + (col - 256)];
    else
      v = (col < 256) ? fuse2_w[(256 + k) * 256 + col]
                      : fc2_w0[(512 + k) * 256 + (col - 256)];
    int ct = col >> 7, cc = col & 127, kc = k >> 6, kk = k & 63;
    u16* dst = (g < 131072) ? BtE1 : BtE2;
    dst[ct * 32768 + kc * 8192 + cc * 64 + (kk ^ ((cc & 7) * 8))] = f2bf(v);
  } else if (g < 393216) {
    int t = g - 262144;
    int c = t >> 8, k = t & 255;
    float v = (c < 256) ? weight[k * 256 + c] : align_lin[k * 256 + (c - 256)];
    BtW0[t] = f2bf(v);
  } else if (g < 786432) {
    int t = g - 393216;
    int c = t >> 8, k = t & 255;
    int seg = c >> 8, cc = c & 255;
    float v;
    if      (seg == 0) v = fuse1_w[k * 256 + cc];
    else if (seg == 1) v = fuse2_w[k * 256 + cc];
    else if (seg == 2) v = fc1_w0[k * 256 + cc];
    else if (seg == 3) v = fc1_w0[(256 + k) * 256 + cc];
    else if (seg == 4) v = fc2_w0[k * 256 + cc];
    else               v = fc2_w0[(256 + k) * 256 + cc];
    BtLoop[t] = f2bf(v);
  } else {
    int t = g - 786432;
    int c = t >> 9, k = t & 511;
    BtFc3[t] = f2bf(fc3_w[k * 256 + c]);
  }
}

// ---------------------------------------------------------------------------
// SelfAlignment (unchanged)
// ---------------------------------------------------------------------------
__global__ __launch_bounds__(128) void align_kernel(
    const float* __restrict__ text, const float* __restrict__ T0,
    const float* __restrict__ textmask, const float* __restrict__ align_bias,
    float* __restrict__ outss) {
  const int bi = blockIdx.x;
  const int b = bi >> 7;
  const int tid = threadIdx.x;
  __shared__ float ta[256];
  __shared__ float pr[128];
  __shared__ float red[128];
  ta[tid]       = T0[(long)bi * 512 + 256 + tid];
  ta[tid + 128] = T0[(long)bi * 512 + 384 + tid];
  __syncthreads();
  const float* trow = text + (long)(b * 128 + tid) * 256;
  float dot = 0.f;
  for (int d = 0; d < 256; d += 4) {
    float4 t4 = *(const float4*)(trow + d);
    dot += t4.x * ta[d] + t4.y * ta[d + 1] + t4.z * ta[d + 2] + t4.w * ta[d + 3];
  }
  float logit = dot + (1.0f - textmask[b * 128 + tid]) * -1e20f;
  pr[tid] = logit;
  red[tid] = logit;
  __syncthreads();
  for (int off = 64; off; off >>= 1) {
    if (tid < off) red[tid] = fmaxf(red[tid], red[tid + off]);
    __syncthreads();
  }
  float mx = red[0];
  __syncthreads();
  float e = __expf(pr[tid] - mx);
  red[tid] = e;
  __syncthreads();
  for (int off = 64; off; off >>= 1) {
    if (tid < off) red[tid] += red[tid + off];
    __syncthreads();
  }
  float inv = 1.0f / red[0];
  __syncthreads();
  pr[tid] = e * inv;
  __syncthreads();
  const float mi = textmask[bi];
  for (int h = 0; h < 2; ++h) {
    int d = tid + h * 128;
    float s = 0.f;
    for (int j = 0; j < 128; ++j)
      s += pr[j] * text[(long)(b * 128 + j) * 256 + d];
    outss[(long)bi * 256 + d] = s * mi + align_bias[d];
  }
}

// ---------------------------------------------------------------------------
// Fused gate/aggregate v3: block = (b,i,half), 256 thr = 4 waves, 64 j each.
// Lane owns a 4-wide d-slice (float4) -> low VGPR, high occupancy.
// Per j: z = 64-lane dot-reduce, s = adj*sigmoid(z+b), acc += s*relu(of+e).
// Iterations independent -> loads of j+1 overlap j's shfl/exp chain.
// Output: per-half partials OUa / OUb (summed by the Yb GEMM staging).
// ---------------------------------------------------------------------------
__global__ __launch_bounds__(256) void fused_gate(
    const u16* __restrict__ E1, const u16* __restrict__ E2,
    const float* __restrict__ P, const float* __restrict__ adj1,
    const float* __restrict__ adj2, const float* __restrict__ fc1w1,
    const float* __restrict__ fc1b1, const float* __restrict__ fc2w1,
    const float* __restrict__ fc2b1, float* __restrict__ OUa,
    float* __restrict__ OUb) {
  const int tid = threadIdx.x, lane = tid & 63, w = tid >> 6;
  const int bi = blockIdx.x >> 1, half = blockIdx.x & 1;
  const int b = bi >> 7;
  const int d4 = lane * 4;
  const long rowi = (long)bi * 1536;
  const long ebase = (long)bi * 65536;
  const int abase = bi * 128;
  float* __restrict__ OU = half ? OUb : OUa;

  __shared__ float sA[64], sB[64];
  __shared__ float redA[4][256], redB[4][256];
  __shared__ float dInv[2];

  if (tid < 64) sA[tid] = adj1[abase + half * 64 + tid];
  else if (tid < 128) sB[tid - 64] = adj2[abase + half * 64 + (tid - 64)];
  if (w == 0) {
    float v = adj1[abase + lane] + adj1[abase + 64 + lane];
#pragma unroll
    for (int off = 32; off; off >>= 1) v += __shfl_xor(v, off);
    if (lane == 0) dInv[0] = 1.f / (1.f + v);
  } else if (w == 1) {
    float v = adj2[abase + lane] + adj2[abase + 64 + lane];
#pragma unroll
    for (int off = 32; off; off >>= 1) v += __shfl_xor(v, off);
    if (lane == 0) dInv[1] = 1.f / (1.f + v);
  }
  __syncthreads();

  const float4 ti1 = *(const float4*)(P + rowi + 512 + d4);
  const float4 ti2 = *(const float4*)(P + rowi + 1024 + d4);
  const float4 w1v = *(const float4*)(fc1w1 + d4);
  const float4 w2v = *(const float4*)(fc2w1 + d4);
  const float b1 = fc1b1[0], b2 = fc2b1[0];

  float4 acc1 = {0.f, 0.f, 0.f, 0.f}, acc2 = {0.f, 0.f, 0.f, 0.f};

#pragma unroll 2
  for (int t = 0; t < 16; ++t) {
    const int jl = w * 16 + t;
    const int j = half * 64 + jl;
    const long er = ebase + (long)j * 512;
    const long rowj = (long)((b << 7) + j) * 1536;
    float4 e1c = unpack4(E1 + er + 256 + d4);
    float4 e2c = unpack4(E2 + er + 256 + d4);
    float4 t1 = *(const float4*)(P + rowj + 768 + d4);
    float4 t2 = *(const float4*)(P + rowj + 1280 + d4);
    float z1 = fmaxf(ti1.x + t1.x + e1c.x, 0.f) * w1v.x +
               fmaxf(ti1.y + t1.y + e1c.y, 0.f) * w1v.y +
               fmaxf(ti1.z + t1.z + e1c.z, 0.f) * w1v.z +
               fmaxf(ti1.w + t1.w + e1c.w, 0.f) * w1v.w;
    float z2 = fmaxf(ti2.x + t2.x + e2c.x, 0.f) * w2v.x +
               fmaxf(ti2.y + t2.y + e2c.y, 0.f) * w2v.y +
               fmaxf(ti2.z + t2.z + e2c.z, 0.f) * w2v.z +
               fmaxf(ti2.w + t2.w + e2c.w, 0.f) * w2v.w;
#pragma unroll
    for (int off = 1; off < 64; off <<= 1) {
      z1 += __shfl_xor(z1, off);
      z2 += __shfl_xor(z2, off);
    }
    float s1 = sA[jl] * __builtin_amdgcn_rcpf(1.f + __expf(-(z1 + b1)));
    float s2 = sB[jl] * __builtin_amdgcn_rcpf(1.f + __expf(-(z2 + b2)));
    float4 e1f = unpack4(E1 + er + d4);
    float4 e2f = unpack4(E2 + er + d4);
    float4 o1 = *(const float4*)(P + rowj + d4);
    float4 o2 = *(const float4*)(P + rowj + 256 + d4);
    acc1.x += s1 * fmaxf(o1.x + e1f.x, 0.f);
    acc1.y += s1 * fmaxf(o1.y + e1f.y, 0.f);
    acc1.z += s1 * fmaxf(o1.z + e1f.z, 0.f);
    acc1.w += s1 * fmaxf(o1.w + e1f.w, 0.f);
    acc2.x += s2 * fmaxf(o2.x + e2f.x, 0.f);
    acc2.y += s2 * fmaxf(o2.y + e2f.y, 0.f);
    acc2.z += s2 * fmaxf(o2.z + e2f.z, 0.f);
    acc2.w += s2 * fmaxf(o2.w + e2f.w, 0.f);
  }

  *(float4*)&redA[w][d4] = acc1;
  *(float4*)&redB[w][d4] = acc2;
  __syncthreads();
  float r1 = redA[0][tid] + redA[1][tid] + redA[2][tid] + redA[3][tid];
  float r2 = redB[0][tid] + redB[1][tid] + redB[2][tid] + redB[3][tid];
  OU[(long)bi * 512 + tid] = r1 * dInv[0];
  OU[(long)bi * 512 + 256 + tid] = r2 * dInv[1];
}

// ---------------------------------------------------------------------------
// out = layernorm(relu(Y) + prev + bias) * gamma + beta
// ---------------------------------------------------------------------------
__global__ __launch_bounds__(256) void ln_kernel(
    const float* __restrict__ Y, const float* __restrict__ prev,
    const float* __restrict__ bias, const float* __restrict__ gamma,
    const float* __restrict__ beta, float* __restrict__ dst) {
  const int row = blockIdx.x, tid = threadIdx.x, lane = tid & 63, w = tid >> 6;
  const long idx = (long)row * 256 + tid;
  float v = fmaxf(Y[idx], 0.f) + prev[idx] + bias[tid];
  float s = v;
#pragma unroll
  for (int off = 32; off; off >>= 1) s += __shfl_xor(s, off);
  __shared__ float wsA[4], wsB[4];
  if (lane == 0) wsA[w] = s;
  __syncthreads();
  float mean = (wsA[0] + wsA[1] + wsA[2] + wsA[3]) * (1.0f / 256.0f);
  float c = v - mean;
  float s2 = c * c;
#pragma unroll
  for (int off = 32; off; off >>= 1) s2 += __shfl_xor(s2, off);
  if (lane == 0) wsB[w] = s2;
  __syncthreads();
  float var = (wsB[0] + wsB[1] + wsB[2] + wsB[3]) * (1.0f / 256.0f);
  dst[idx] = c * rsqrtf(var + 1e-5f) * gamma[tid] + beta[tid];
}

// ---------------------------------------------------------------------------
extern "C" void kernel_launch(void* const* d_in, const int* in_sizes, int n_in,
                              void* d_out, int out_size, void* d_ws, size_t ws_size,
                              hipStream_t stream) {
  const float* text      = (const float*)d_in[0];
  const float* adj1      = (const float*)d_in[1];
  const float* adj2      = (const float*)d_in[2];
  const float* edge1     = (const float*)d_in[3];
  const float* edge2     = (const float*)d_in[4];
  const float* textmask  = (const float*)d_in[5];
  const float* weight    = (const float*)d_in[6];
  const float* bias      = (const float*)d_in[7];
  const float* gamma     = (const float*)d_in[8];
  const float* beta      = (const float*)d_in[9];
  const float* fuse1_w   = (const float*)d_in[10];
  const float* fuse2_w   = (const float*)d_in[11];
  const float* fc3_w     = (const float*)d_in[12];
  const float* fc1_w0    = (const float*)d_in[13];
  const float* fc1_w1    = (const float*)d_in[14];
  const float* fc1_b1    = (const float*)d_in[15];
  const float* fc2_w0    = (const float*)d_in[16];
  const float* fc2_w1    = (const float*)d_in[17];
  const float* fc2_b1    = (const float*)d_in[18];
  const float* align_lin = (const float*)d_in[19];
  const float* align_bias= (const float*)d_in[20];
  float* outF = (float*)d_out;  // out: [0,262144), outss: [262144,524288)

  char* w8 = (char*)d_ws;
  u16* E1   = (u16*)(w8 + 67108864);          // 128 MB
  u16* E2   = (u16*)(w8 + 201326592);         // 128 MB
  u16* BtE1 = (u16*)(w8 + 335544320);
  u16* BtE2 = BtE1 + 131072;
  u16* BtW0 = BtE2 + 131072;
  u16* BtLoop = BtW0 + 131072;                // 1536 x 256
  u16* BtFc3  = BtLoop + 393216;              // 256 x 512
  // small f32 buffers live in the first 64 MB (no longer used for Ax)
  float* P    = (float*)w8;                   // 1024 x 1536
  float* T0   = P + 1572864;                  // 1024 x 512
  float* OUa  = T0 + 524288;                  // 1024 x 512 (j-half 0 partial)
  float* OUb  = OUa + 524288;                 // 1024 x 512 (j-half 1 partial)
  float* outb = OUb + 524288;                 // 1024 x 256
  float* Yb   = outb + 262144;                // 1024 x 256

  // 1) weight tables
  prep_bt<<<3584, 256, 0, stream>>>(weight, align_lin, fuse1_w, fuse2_w,
                                    fc1_w0, fc2_w0, fc3_w,
                                    BtE1, BtE2, BtW0, BtLoop, BtFc3);
  // 2) edge projections straight from f32 (convert pass eliminated)
  gemm_edge<<<4096, 256, 0, stream>>>(edge1, BtE1, E1);
  gemm_edge<<<4096, 256, 0, stream>>>(edge2, BtE2, E2);
  // 3) T0 = text @ [weight | align_lin], relu of first 256 cols fused -> outb
  gemm_mfma<256, 2, false, true, false><<<dim3(32, 2), 256, 0, stream>>>(
      text, BtW0, T0, 512, outb, nullptr);
  // 4) self-alignment -> outss
  align_kernel<<<1024, 128, 0, stream>>>(text, T0, textmask, align_bias,
                                         outF + 262144);
  // 5) K = 3 GCN iterations
  for (int it = 0; it < 3; ++it) {
    gemm_mfma<256, 2, false, false, false><<<dim3(32, 6), 256, 0, stream>>>(
        outb, BtLoop, P, 1536, nullptr, nullptr);
    fused_gate<<<2048, 256, 0, stream>>>(E1, E2, P, adj1, adj2, fc1_w1, fc1_b1,
                                         fc2_w1, fc2_b1, OUa, OUb);
    gemm_mfma<512, 2, false, false, true><<<dim3(32, 1), 256, 0, stream>>>(
        OUa, BtFc3, Yb, 256, nullptr, OUb);
    ln_kernel<<<1024, 256, 0, stream>>>(Yb, outb, bias, gamma, beta,
                                        (it == 2) ? outF : outb);
  }
}

// Round 3
// 737.871 us; speedup vs baseline: 1.1431x; 1.0024x over previous
//
#include <hip/hip_runtime.h>

typedef unsigned short u16;
typedef unsigned int u32;
typedef __attribute__((ext_vector_type(8))) short bf16x8;
typedef __attribute__((ext_vector_type(4))) float f32x4;

__device__ __forceinline__ u16 f2bf(float f) {
  u32 u = __float_as_uint(f);
  return (u16)((u + 0x7fffu + ((u >> 16) & 1u)) >> 16);
}

// unpack 4 bf16 -> 4 f32 (one 8-B load)
__device__ __forceinline__ float4 unpack4(const u16* p) {
  uint2 a = *(const uint2*)p;
  float4 r;
  r.x = __uint_as_float(a.x << 16);
  r.y = __uint_as_float(a.x & 0xffff0000u);
  r.z = __uint_as_float(a.y << 16);
  r.w = __uint_as_float(a.y & 0xffff0000u);
  return r;
}

// lgkm-only barrier: does NOT drain vmcnt, so global prefetches stay in
// flight across it. asm-memory on both sides pins LDS op ordering.
__device__ __forceinline__ void barrier_lgkm() {
  asm volatile("s_waitcnt lgkmcnt(0)" ::: "memory");
  __builtin_amdgcn_s_barrier();
  asm volatile("" ::: "memory");
}

// ---------------------------------------------------------------------------
// Edge GEMM: E[131072 x 512] = edge(f32) @ Bt(bf16)^T, K=256.
// A: reg-prefetched f32 -> bf16 -> swizzled LDS (double-buffered, one
// lgkm-only barrier per K-step). B: read directly from global (L2-resident
// 256 KB weight table, tiled+swizzled layout). XCD-grouped block mapping.
// ---------------------------------------------------------------------------
__global__ __launch_bounds__(256) void gemm_edge(
    const float* __restrict__ Af, const u16* __restrict__ Bt,
    u16* __restrict__ E) {
  __shared__ __align__(16) u16 Asm[2][8192];
  const int tid = threadIdx.x, lane = tid & 63, w = tid >> 6;
  const int m = lane & 15, q = lane >> 4;
  const int p = blockIdx.x;
  const int rt = (p & 7) * 128 + (p >> 5);  // XCD (p%8) owns rt block
  const int ct = (p >> 3) & 3;
  const int wrow = (w & 1) * 64, wcol = (w >> 1) * 64;
  const float* Ab = Af + (long)rt * 32768;  // 128 rows x 256 cols f32
  const char* Bb = (const char*)Bt + (long)ct * 65536;
  const int r0 = tid >> 4, c4 = (tid & 15) * 4;
  f32x4 acc[4][4];
#pragma unroll
  for (int r = 0; r < 4; ++r)
#pragma unroll
    for (int c = 0; c < 4; ++c) acc[r][c] = (f32x4){0.f, 0.f, 0.f, 0.f};

  float4 pre[8];
#pragma unroll
  for (int it = 0; it < 8; ++it)
    pre[it] = *(const float4*)(Ab + (long)(it * 16 + r0) * 256 + c4);

#pragma unroll
  for (int kc = 0; kc < 4; ++kc) {
    char* As = (char*)Asm[kc & 1];
    // convert + swizzled ds_write of A[kc] (from regs prefetched last iter)
#pragma unroll
    for (int it = 0; it < 8; ++it) {
      int r = it * 16 + r0;
      ushort4 h;
      h.x = f2bf(pre[it].x); h.y = f2bf(pre[it].y);
      h.z = f2bf(pre[it].z); h.w = f2bf(pre[it].w);
      *(ushort4*)(As + r * 128 + ((c4 * 2) ^ ((r & 7) * 16))) = h;
    }
    // issue A[kc+1] prefetch; lands during the MFMA phase below
    if (kc < 3) {
#pragma unroll
      for (int it = 0; it < 8; ++it)
        pre[it] = *(const float4*)(Ab + (long)(it * 16 + r0) * 256 +
                                   (kc + 1) * 64 + c4);
    }
    barrier_lgkm();
#pragma unroll
    for (int s = 0; s < 2; ++s) {
      const int ko2 = (s * 32 + q * 8) * 2;
      bf16x8 av[4], bv[4];
#pragma unroll
      for (int c = 0; c < 4; ++c) {
        int col = wcol + c * 16 + m;
        bv[c] = *(const bf16x8*)(Bb + kc * 16384 + col * 128 +
                                 (ko2 ^ ((col & 7) * 16)));
      }
#pragma unroll
      for (int r = 0; r < 4; ++r) {
        int row = wrow + r * 16 + m;
        av[r] = *(const bf16x8*)(As + row * 128 + (ko2 ^ ((row & 7) * 16)));
      }
#pragma unroll
      for (int r = 0; r < 4; ++r)
#pragma unroll
        for (int c = 0; c < 4; ++c)
          acc[r][c] = __builtin_amdgcn_mfma_f32_16x16x32_bf16(
              av[r], bv[c], acc[r][c], 0, 0, 0);
    }
    // no second barrier: double-buffered; barrier(kc+1) fences reuse
  }
#pragma unroll
  for (int r = 0; r < 4; ++r)
#pragma unroll
    for (int c = 0; c < 4; ++c)
#pragma unroll
      for (int g = 0; g < 4; ++g) {
        long gr = (long)rt * 128 + wrow + r * 16 + q * 4 + g;
        int gc = ct * 128 + wcol + c * 16 + m;
        E[gr * 512 + gc] = f2bf(acc[r][c][g]);
      }
}

// ---------------------------------------------------------------------------
// Generic small GEMM: C[M x Ntot] = A[M x K](f32) * Bt[Ntot x K](bf16)^T.
// Tile = RF*16 rows x CF*64 cols, 4 waves (each RF*16 x CF*16).
// A double-buffered in LDS with reg-prefetch; B direct from global (L2).
// One lgkm-only barrier per K-step. RELU0: relu(cols<256) -> relu_dst.
// SUM2: A_eff = A + A2.
// ---------------------------------------------------------------------------
template<int K, int RF, int CF, bool OUT_BF16, bool RELU0, bool SUM2>
__global__ __launch_bounds__(256) void gemm_mfma(
    const float* __restrict__ A, const u16* __restrict__ Bt,
    void* __restrict__ Cv, int Ntot, float* __restrict__ relu_dst,
    const float* __restrict__ A2) {
  constexpr int ROWS = RF * 16;
  constexpr int LD = 72;
  __shared__ __align__(16) u16 Asm[2][ROWS * LD];
  const int tid = threadIdx.x;
  const int lane = tid & 63;
  const int w = tid >> 6;
  const int m = lane & 15;
  const int q = lane >> 4;
  const int wcol = w * (CF * 16);
  const long rowbase = (long)blockIdx.x * ROWS;
  const long colbase = (long)blockIdx.y * (CF * 64);
  const int r0 = tid >> 4, c4 = (tid & 15) * 4;
  f32x4 acc[RF][CF];
#pragma unroll
  for (int r = 0; r < RF; ++r)
#pragma unroll
    for (int c = 0; c < CF; ++c) acc[r][c] = (f32x4){0.f, 0.f, 0.f, 0.f};

  float4 pre[RF], pre2[RF];
#pragma unroll
  for (int it = 0; it < RF; ++it) {
    pre[it] = *(const float4*)(A + (rowbase + it * 16 + r0) * K + c4);
    if constexpr (SUM2)
      pre2[it] = *(const float4*)(A2 + (rowbase + it * 16 + r0) * K + c4);
  }

#pragma unroll
  for (int kc = 0; kc < K / 64; ++kc) {
    u16* As = (u16*)Asm[kc & 1];
#pragma unroll
    for (int it = 0; it < RF; ++it) {
      float4 v = pre[it];
      if constexpr (SUM2) {
        v.x += pre2[it].x; v.y += pre2[it].y;
        v.z += pre2[it].z; v.w += pre2[it].w;
      }
      ushort4 h;
      h.x = f2bf(v.x); h.y = f2bf(v.y); h.z = f2bf(v.z); h.w = f2bf(v.w);
      *(ushort4*)&As[(it * 16 + r0) * LD + c4] = h;
    }
    if (kc + 1 < K / 64) {
#pragma unroll
      for (int it = 0; it < RF; ++it) {
        pre[it] = *(const float4*)(A + (rowbase + it * 16 + r0) * K +
                                   (kc + 1) * 64 + c4);
        if constexpr (SUM2)
          pre2[it] = *(const float4*)(A2 + (rowbase + it * 16 + r0) * K +
                                      (kc + 1) * 64 + c4);
      }
    }
    barrier_lgkm();
#pragma unroll
    for (int s = 0; s < 2; ++s) {
      const int ko = s * 32 + q * 8;
      bf16x8 av[RF], bv[CF];
#pragma unroll
      for (int c = 0; c < CF; ++c)
        bv[c] = *(const bf16x8*)(Bt + (long)(colbase + wcol + c * 16 + m) * K +
                                 kc * 64 + ko);
#pragma unroll
      for (int r = 0; r < RF; ++r)
        av[r] = *(const bf16x8*)&As[(r * 16 + m) * LD + ko];
#pragma unroll
      for (int r = 0; r < RF; ++r)
#pragma unroll
        for (int c = 0; c < CF; ++c)
          acc[r][c] = __builtin_amdgcn_mfma_f32_16x16x32_bf16(
              av[r], bv[c], acc[r][c], 0, 0, 0);
    }
  }
#pragma unroll
  for (int r = 0; r < RF; ++r)
#pragma unroll
    for (int c = 0; c < CF; ++c)
#pragma unroll
      for (int g = 0; g < 4; ++g) {
        long gr = rowbase + r * 16 + q * 4 + g;
        long gc = colbase + wcol + c * 16 + m;
        float v = acc[r][c][g];
        if constexpr (OUT_BF16) ((u16*)Cv)[gr * Ntot + gc] = f2bf(v);
        else                    ((float*)Cv)[gr * Ntot + gc] = v;
        if constexpr (RELU0) {
          if (gc < 256) relu_dst[gr * 256 + gc] = fmaxf(v, 0.f);
        }
      }
}

// ---------------------------------------------------------------------------
// Weight tables (unchanged).
// ---------------------------------------------------------------------------
__global__ __launch_bounds__(256) void prep_bt(
    const float* __restrict__ weight, const float* __restrict__ align_lin,
    const float* __restrict__ fuse1_w, const float* __restrict__ fuse2_w,
    const float* __restrict__ fc1_w0, const float* __restrict__ fc2_w0,
    const float* __restrict__ fc3_w,
    u16* BtE1, u16* BtE2, u16* BtW0, u16* BtLoop, u16* BtFc3) {
  int g = blockIdx.x * 256 + threadIdx.x;  // 0..917503
  if (g < 262144) {
    int t = g & 131071;
    int col = t >> 8, k = t & 255;
    float v;
    if (g < 131072)
      v = (col < 256) ? fuse1_w[(256 + k) * 256 + col]
                      : fc1_w0[(512 + k) * 256 + (col - 256)];
    else
      v = (col < 256) ? fuse2_w[(256 + k) * 256 + col]
                      : fc2_w0[(512 + k) * 256 + (col - 256)];
    int ct = col >> 7, cc = col & 127, kc = k >> 6, kk = k & 63;
    u16* dst = (g < 131072) ? BtE1 : BtE2;
    dst[ct * 32768 + kc * 8192 + cc * 64 + (kk ^ ((cc & 7) * 8))] = f2bf(v);
  } else if (g < 393216) {
    int t = g - 262144;
    int c = t >> 8, k = t & 255;
    float v = (c < 256) ? weight[k * 256 + c] : align_lin[k * 256 + (c - 256)];
    BtW0[t] = f2bf(v);
  } else if (g < 786432) {
    int t = g - 393216;
    int c = t >> 8, k = t & 255;
    int seg = c >> 8, cc = c & 255;
    float v;
    if      (seg == 0) v = fuse1_w[k * 256 + cc];
    else if (seg == 1) v = fuse2_w[k * 256 + cc];
    else if (seg == 2) v = fc1_w0[k * 256 + cc];
    else if (seg == 3) v = fc1_w0[(256 + k) * 256 + cc];
    else if (seg == 4) v = fc2_w0[k * 256 + cc];
    else               v = fc2_w0[(256 + k) * 256 + cc];
    BtLoop[t] = f2bf(v);
  } else {
    int t = g - 786432;
    int c = t >> 9, k = t & 511;
    BtFc3[t] = f2bf(fc3_w[k * 256 + c]);
  }
}

// ---------------------------------------------------------------------------
// SelfAlignment (unchanged)
// ---------------------------------------------------------------------------
__global__ __launch_bounds__(128) void align_kernel(
    const float* __restrict__ text, const float* __restrict__ T0,
    const float* __restrict__ textmask, const float* __restrict__ align_bias,
    float* __restrict__ outss) {
  const int bi = blockIdx.x;
  const int b = bi >> 7;
  const int tid = threadIdx.x;
  __shared__ float ta[256];
  __shared__ float pr[128];
  __shared__ float red[128];
  ta[tid]       = T0[(long)bi * 512 + 256 + tid];
  ta[tid + 128] = T0[(long)bi * 512 + 384 + tid];
  __syncthreads();
  const float* trow = text + (long)(b * 128 + tid) * 256;
  float dot = 0.f;
  for (int d = 0; d < 256; d += 4) {
    float4 t4 = *(const float4*)(trow + d);
    dot += t4.x * ta[d] + t4.y * ta[d + 1] + t4.z * ta[d + 2] + t4.w * ta[d + 3];
  }
  float logit = dot + (1.0f - textmask[b * 128 + tid]) * -1e20f;
  pr[tid] = logit;
  red[tid] = logit;
  __syncthreads();
  for (int off = 64; off; off >>= 1) {
    if (tid < off) red[tid] = fmaxf(red[tid], red[tid + off]);
    __syncthreads();
  }
  float mx = red[0];
  __syncthreads();
  float e = __expf(pr[tid] - mx);
  red[tid] = e;
  __syncthreads();
  for (int off = 64; off; off >>= 1) {
    if (tid < off) red[tid] += red[tid + off];
    __syncthreads();
  }
  float inv = 1.0f / red[0];
  __syncthreads();
  pr[tid] = e * inv;
  __syncthreads();
  const float mi = textmask[bi];
  for (int h = 0; h < 2; ++h) {
    int d = tid + h * 128;
    float s = 0.f;
    for (int j = 0; j < 128; ++j)
      s += pr[j] * text[(long)(b * 128 + j) * 256 + d];
    outss[(long)bi * 256 + d] = s * mi + align_bias[d];
  }
}

// ---------------------------------------------------------------------------
// Fused gate/aggregate (unchanged from R2): block = (b,i,half), 4 waves.
// ---------------------------------------------------------------------------
__global__ __launch_bounds__(256) void fused_gate(
    const u16* __restrict__ E1, const u16* __restrict__ E2,
    const float* __restrict__ P, const float* __restrict__ adj1,
    const float* __restrict__ adj2, const float* __restrict__ fc1w1,
    const float* __restrict__ fc1b1, const float* __restrict__ fc2w1,
    const float* __restrict__ fc2b1, float* __restrict__ OUa,
    float* __restrict__ OUb) {
  const int tid = threadIdx.x, lane = tid & 63, w = tid >> 6;
  const int bi = blockIdx.x >> 1, half = blockIdx.x & 1;
  const int b = bi >> 7;
  const int d4 = lane * 4;
  const long rowi = (long)bi * 1536;
  const long ebase = (long)bi * 65536;
  const int abase = bi * 128;
  float* __restrict__ OU = half ? OUb : OUa;

  __shared__ float sA[64], sB[64];
  __shared__ float redA[4][256], redB[4][256];
  __shared__ float dInv[2];

  if (tid < 64) sA[tid] = adj1[abase + half * 64 + tid];
  else if (tid < 128) sB[tid - 64] = adj2[abase + half * 64 + (tid - 64)];
  if (w == 0) {
    float v = adj1[abase + lane] + adj1[abase + 64 + lane];
#pragma unroll
    for (int off = 32; off; off >>= 1) v += __shfl_xor(v, off);
    if (lane == 0) dInv[0] = 1.f / (1.f + v);
  } else if (w == 1) {
    float v = adj2[abase + lane] + adj2[abase + 64 + lane];
#pragma unroll
    for (int off = 32; off; off >>= 1) v += __shfl_xor(v, off);
    if (lane == 0) dInv[1] = 1.f / (1.f + v);
  }
  __syncthreads();

  const float4 ti1 = *(const float4*)(P + rowi + 512 + d4);
  const float4 ti2 = *(const float4*)(P + rowi + 1024 + d4);
  const float4 w1v = *(const float4*)(fc1w1 + d4);
  const float4 w2v = *(const float4*)(fc2w1 + d4);
  const float b1 = fc1b1[0], b2 = fc2b1[0];

  float4 acc1 = {0.f, 0.f, 0.f, 0.f}, acc2 = {0.f, 0.f, 0.f, 0.f};

#pragma unroll 2
  for (int t = 0; t < 16; ++t) {
    const int jl = w * 16 + t;
    const int j = half * 64 + jl;
    const long er = ebase + (long)j * 512;
    const long rowj = (long)((b << 7) + j) * 1536;
    float4 e1c = unpack4(E1 + er + 256 + d4);
    float4 e2c = unpack4(E2 + er + 256 + d4);
    float4 t1 = *(const float4*)(P + rowj + 768 + d4);
    float4 t2 = *(const float4*)(P + rowj + 1280 + d4);
    float z1 = fmaxf(ti1.x + t1.x + e1c.x, 0.f) * w1v.x +
               fmaxf(ti1.y + t1.y + e1c.y, 0.f) * w1v.y +
               fmaxf(ti1.z + t1.z + e1c.z, 0.f) * w1v.z +
               fmaxf(ti1.w + t1.w + e1c.w, 0.f) * w1v.w;
    float z2 = fmaxf(ti2.x + t2.x + e2c.x, 0.f) * w2v.x +
               fmaxf(ti2.y + t2.y + e2c.y, 0.f) * w2v.y +
               fmaxf(ti2.z + t2.z + e2c.z, 0.f) * w2v.z +
               fmaxf(ti2.w + t2.w + e2c.w, 0.f) * w2v.w;
#pragma unroll
    for (int off = 1; off < 64; off <<= 1) {
      z1 += __shfl_xor(z1, off);
      z2 += __shfl_xor(z2, off);
    }
    float s1 = sA[jl] * __builtin_amdgcn_rcpf(1.f + __expf(-(z1 + b1)));
    float s2 = sB[jl] * __builtin_amdgcn_rcpf(1.f + __expf(-(z2 + b2)));
    float4 e1f = unpack4(E1 + er + d4);
    float4 e2f = unpack4(E2 + er + d4);
    float4 o1 = *(const float4*)(P + rowj + d4);
    float4 o2 = *(const float4*)(P + rowj + 256 + d4);
    acc1.x += s1 * fmaxf(o1.x + e1f.x, 0.f);
    acc1.y += s1 * fmaxf(o1.y + e1f.y, 0.f);
    acc1.z += s1 * fmaxf(o1.z + e1f.z, 0.f);
    acc1.w += s1 * fmaxf(o1.w + e1f.w, 0.f);
    acc2.x += s2 * fmaxf(o2.x + e2f.x, 0.f);
    acc2.y += s2 * fmaxf(o2.y + e2f.y, 0.f);
    acc2.z += s2 * fmaxf(o2.z + e2f.z, 0.f);
    acc2.w += s2 * fmaxf(o2.w + e2f.w, 0.f);
  }

  *(float4*)&redA[w][d4] = acc1;
  *(float4*)&redB[w][d4] = acc2;
  __syncthreads();
  float r1 = redA[0][tid] + redA[1][tid] + redA[2][tid] + redA[3][tid];
  float r2 = redB[0][tid] + redB[1][tid] + redB[2][tid] + redB[3][tid];
  OU[(long)bi * 512 + tid] = r1 * dInv[0];
  OU[(long)bi * 512 + 256 + tid] = r2 * dInv[1];
}

// ---------------------------------------------------------------------------
// out = layernorm(relu(Y) + prev + bias) * gamma + beta
// ---------------------------------------------------------------------------
__global__ __launch_bounds__(256) void ln_kernel(
    const float* __restrict__ Y, const float* __restrict__ prev,
    const float* __restrict__ bias, const float* __restrict__ gamma,
    const float* __restrict__ beta, float* __restrict__ dst) {
  const int row = blockIdx.x, tid = threadIdx.x, lane = tid & 63, w = tid >> 6;
  const long idx = (long)row * 256 + tid;
  float v = fmaxf(Y[idx], 0.f) + prev[idx] + bias[tid];
  float s = v;
#pragma unroll
  for (int off = 32; off; off >>= 1) s += __shfl_xor(s, off);
  __shared__ float wsA[4], wsB[4];
  if (lane == 0) wsA[w] = s;
  __syncthreads();
  float mean = (wsA[0] + wsA[1] + wsA[2] + wsA[3]) * (1.0f / 256.0f);
  float c = v - mean;
  float s2 = c * c;
#pragma unroll
  for (int off = 32; off; off >>= 1) s2 += __shfl_xor(s2, off);
  if (lane == 0) wsB[w] = s2;
  __syncthreads();
  float var = (wsB[0] + wsB[1] + wsB[2] + wsB[3]) * (1.0f / 256.0f);
  dst[idx] = c * rsqrtf(var + 1e-5f) * gamma[tid] + beta[tid];
}

// ---------------------------------------------------------------------------
extern "C" void kernel_launch(void* const* d_in, const int* in_sizes, int n_in,
                              void* d_out, int out_size, void* d_ws, size_t ws_size,
                              hipStream_t stream) {
  const float* text      = (const float*)d_in[0];
  const float* adj1      = (const float*)d_in[1];
  const float* adj2      = (const float*)d_in[2];
  const float* edge1     = (const float*)d_in[3];
  const float* edge2     = (const float*)d_in[4];
  const float* textmask  = (const float*)d_in[5];
  const float* weight    = (const float*)d_in[6];
  const float* bias      = (const float*)d_in[7];
  const float* gamma     = (const float*)d_in[8];
  const float* beta      = (const float*)d_in[9];
  const float* fuse1_w   = (const float*)d_in[10];
  const float* fuse2_w   = (const float*)d_in[11];
  const float* fc3_w     = (const float*)d_in[12];
  const float* fc1_w0    = (const float*)d_in[13];
  const float* fc1_w1    = (const float*)d_in[14];
  const float* fc1_b1    = (const float*)d_in[15];
  const float* fc2_w0    = (const float*)d_in[16];
  const float* fc2_w1    = (const float*)d_in[17];
  const float* fc2_b1    = (const float*)d_in[18];
  const float* align_lin = (const float*)d_in[19];
  const float* align_bias= (const float*)d_in[20];
  float* outF = (float*)d_out;  // out: [0,262144), outss: [262144,524288)

  char* w8 = (char*)d_ws;
  u16* E1   = (u16*)(w8 + 67108864);          // 128 MB
  u16* E2   = (u16*)(w8 + 201326592);         // 128 MB
  u16* BtE1 = (u16*)(w8 + 335544320);
  u16* BtE2 = BtE1 + 131072;
  u16* BtW0 = BtE2 + 131072;
  u16* BtLoop = BtW0 + 131072;                // 1536 x 256
  u16* BtFc3  = BtLoop + 393216;              // 256 x 512
  // small f32 buffers live in the first 64 MB
  float* P    = (float*)w8;                   // 1024 x 1536
  float* T0   = P + 1572864;                  // 1024 x 512
  float* OUa  = T0 + 524288;                  // 1024 x 512 (j-half 0 partial)
  float* OUb  = OUa + 524288;                 // 1024 x 512 (j-half 1 partial)
  float* outb = OUb + 524288;                 // 1024 x 256
  float* Yb   = outb + 262144;                // 1024 x 256

  // 1) weight tables
  prep_bt<<<3584, 256, 0, stream>>>(weight, align_lin, fuse1_w, fuse2_w,
                                    fc1_w0, fc2_w0, fc3_w,
                                    BtE1, BtE2, BtW0, BtLoop, BtFc3);
  // 2) edge projections straight from f32
  gemm_edge<<<4096, 256, 0, stream>>>(edge1, BtE1, E1);
  gemm_edge<<<4096, 256, 0, stream>>>(edge2, BtE2, E2);
  // 3) T0 = text @ [weight | align_lin], relu of first 256 cols -> outb
  gemm_mfma<256, 2, 2, false, true, false><<<dim3(32, 4), 256, 0, stream>>>(
      text, BtW0, T0, 512, outb, nullptr);
  // 4) self-alignment -> outss
  align_kernel<<<1024, 128, 0, stream>>>(text, T0, textmask, align_bias,
                                         outF + 262144);
  // 5) K = 3 GCN iterations
  for (int it = 0; it < 3; ++it) {
    gemm_mfma<256, 2, 2, false, false, false><<<dim3(32, 12), 256, 0, stream>>>(
        outb, BtLoop, P, 1536, nullptr, nullptr);
    fused_gate<<<2048, 256, 0, stream>>>(E1, E2, P, adj1, adj2, fc1_w1, fc1_b1,
                                         fc2_w1, fc2_b1, OUa, OUb);
    gemm_mfma<512, 1, 2, false, false, true><<<dim3(64, 2), 256, 0, stream>>>(
        OUa, BtFc3, Yb, 256, nullptr, OUb);
    ln_kernel<<<1024, 256, 0, stream>>>(Yb, outb, bias, gamma, beta,
                                        (it == 2) ? outF : outb);
  }
}

// Round 4
// 713.163 us; speedup vs baseline: 1.1827x; 1.0346x over previous
//
#include <hip/hip_runtime.h>

typedef unsigned short u16;
typedef unsigned int u32;
typedef __attribute__((ext_vector_type(8))) short bf16x8;
typedef __attribute__((ext_vector_type(4))) float f32x4;

__device__ __forceinline__ u16 f2bf(float f) {
  u32 u = __float_as_uint(f);
  return (u16)((u + 0x7fffu + ((u >> 16) & 1u)) >> 16);
}

// unpack 4 bf16 -> 4 f32 (one 8-B load)
__device__ __forceinline__ float4 unpack4(const u16* p) {
  uint2 a = *(const uint2*)p;
  float4 r;
  r.x = __uint_as_float(a.x << 16);
  r.y = __uint_as_float(a.x & 0xffff0000u);
  r.z = __uint_as_float(a.y << 16);
  r.w = __uint_as_float(a.y & 0xffff0000u);
  return r;
}

__device__ __forceinline__ void glds16(const void* g, void* l) {
  __builtin_amdgcn_global_load_lds(
      (const __attribute__((address_space(1))) unsigned int*)g,
      (__attribute__((address_space(3))) unsigned int*)l, 16, 0, 0);
}

// lgkm-only barrier: does NOT drain vmcnt, so global prefetches stay in
// flight across it. asm-memory on both sides pins LDS op ordering.
__device__ __forceinline__ void barrier_lgkm() {
  asm volatile("s_waitcnt lgkmcnt(0)" ::: "memory");
  __builtin_amdgcn_s_barrier();
  asm volatile("" ::: "memory");
}

// ---------------------------------------------------------------------------
// Persistent edge GEMM: E[131072 x 512] = edge(f32) @ Bt(bf16)^T, K=256.
// 256 blocks (1/CU) x 512 thr (8 waves). Block fixes ct, loads the whole
// 64 KB ct-slice of B into LDS once, then streams 16 rt tiles x 4 K-steps
// as one 64-step pipeline: ds_write A[s] (from regs loaded at s-2) ->
// issue A-prefetch[s+2] -> lgkm barrier -> MFMA. One barrier/step; vmcnt
// waits are counted (loads land ~2 steps early). Partner blocks (ct 0..3,
// same rt range) map to the same XCD for A L2 reuse.
// ---------------------------------------------------------------------------
__global__ __launch_bounds__(512) void gemm_edge(
    const float* __restrict__ Af, const u16* __restrict__ Bt,
    u16* __restrict__ E) {
  __shared__ __align__(16) u16 Bsm[32768];    // 64 KB: full ct B table
  __shared__ __align__(16) u16 Asm[2][8192];  // 2 x 16 KB A dbuf
  const int tid = threadIdx.x, lane = tid & 63, w = tid >> 6;
  const int m = lane & 15, q = lane >> 4;
  const int bid = blockIdx.x;
  const int grp = (bid & 7) * 8 + (bid >> 5);  // [0,64): same-XCD partners
  const int ct = (bid >> 3) & 3;
  const int wrow = (w & 1) * 64, wcol = (w >> 1) * 32;
  const char* Bb = (const char*)Bt + (long)ct * 65536;
  const int r0 = tid >> 2;              // row 0..127
  const int cq = (tid & 3) * 16;        // float col base within 64-wide kc

  // B -> LDS (linear copy preserves tiled+swizzled layout)
#pragma unroll
  for (int it = 0; it < 8; ++it)
    glds16(Bb + it * 8192 + tid * 16, (char*)Bsm + it * 8192 + tid * 16);

  const float* A0 = Af + (long)grp * 16 * 32768;  // 16 tiles of 128x256
  float4 pre[2][4];
#pragma unroll
  for (int it = 0; it < 4; ++it) {
    pre[0][it] = *(const float4*)(A0 + (long)r0 * 256 + cq + it * 4);
    pre[1][it] = *(const float4*)(A0 + (long)r0 * 256 + 64 + cq + it * 4);
  }
  f32x4 acc[4][2];
#pragma unroll
  for (int r = 0; r < 4; ++r)
#pragma unroll
    for (int c = 0; c < 2; ++c) acc[r][c] = (f32x4){0.f, 0.f, 0.f, 0.f};

  for (int t = 0; t < 16; ++t) {
#pragma unroll
    for (int kc = 0; kc < 4; ++kc) {
      char* As = (char*)Asm[kc & 1];
      // convert + swizzled ds_write of A[t,kc] (regs loaded 2 steps ago)
#pragma unroll
      for (int it = 0; it < 4; ++it) {
        float4 v = pre[kc & 1][it];
        ushort4 h;
        h.x = f2bf(v.x); h.y = f2bf(v.y); h.z = f2bf(v.z); h.w = f2bf(v.w);
        int cb = (cq + it * 4) * 2;  // byte offset within 128-B row
        *(ushort4*)(As + r0 * 128 + (cb ^ ((r0 & 7) * 16))) = h;
      }
      // issue A-prefetch for step s+2 into the set just consumed
      {
        int kc2 = (kc + 2) & 3, t2 = t + ((kc + 2) >> 2);
        if (t2 < 16) {
          const float* An = A0 + (long)t2 * 32768;
#pragma unroll
          for (int it = 0; it < 4; ++it)
            pre[kc & 1][it] =
                *(const float4*)(An + (long)r0 * 256 + kc2 * 64 + cq + it * 4);
        }
      }
      barrier_lgkm();
#pragma unroll
      for (int s = 0; s < 2; ++s) {
        const int ko2 = (s * 32 + q * 8) * 2;
        bf16x8 av[4], bv[2];
#pragma unroll
        for (int c = 0; c < 2; ++c) {
          int col = wcol + c * 16 + m;
          bv[c] = *(const bf16x8*)((const char*)Bsm + kc * 16384 + col * 128 +
                                   (ko2 ^ ((col & 7) * 16)));
        }
#pragma unroll
        for (int r = 0; r < 4; ++r) {
          int row = wrow + r * 16 + m;
          av[r] = *(const bf16x8*)(As + row * 128 + (ko2 ^ ((row & 7) * 16)));
        }
#pragma unroll
        for (int r = 0; r < 4; ++r)
#pragma unroll
          for (int c = 0; c < 2; ++c)
            acc[r][c] = __builtin_amdgcn_mfma_f32_16x16x32_bf16(
                av[r], bv[c], acc[r][c], 0, 0, 0);
      }
    }
    // epilogue for tile t; stores ride the vm queue (never waited on)
    const long grow = (long)(grp * 16 + t) * 128;
#pragma unroll
    for (int r = 0; r < 4; ++r)
#pragma unroll
      for (int c = 0; c < 2; ++c) {
#pragma unroll
        for (int g = 0; g < 4; ++g) {
          long gr = grow + wrow + r * 16 + q * 4 + g;
          int gc = ct * 128 + wcol + c * 16 + m;
          E[gr * 512 + gc] = f2bf(acc[r][c][g]);
        }
        acc[r][c] = (f32x4){0.f, 0.f, 0.f, 0.f};
      }
  }
}

// ---------------------------------------------------------------------------
// Generic small GEMM: C[M x Ntot] = A[M x K](f32) * Bt[Ntot x K](bf16)^T.
// Tile = RF*16 rows x CF*64 cols, 4 waves. A dbuf LDS + reg prefetch;
// B direct from global (L2). RELU0: relu(cols<256) -> relu_dst. SUM2: A+=A2.
// ---------------------------------------------------------------------------
template<int K, int RF, int CF, bool OUT_BF16, bool RELU0, bool SUM2>
__global__ __launch_bounds__(256) void gemm_mfma(
    const float* __restrict__ A, const u16* __restrict__ Bt,
    void* __restrict__ Cv, int Ntot, float* __restrict__ relu_dst,
    const float* __restrict__ A2) {
  constexpr int ROWS = RF * 16;
  constexpr int LD = 72;
  __shared__ __align__(16) u16 Asm[2][ROWS * LD];
  const int tid = threadIdx.x;
  const int lane = tid & 63;
  const int w = tid >> 6;
  const int m = lane & 15;
  const int q = lane >> 4;
  const int wcol = w * (CF * 16);
  const long rowbase = (long)blockIdx.x * ROWS;
  const long colbase = (long)blockIdx.y * (CF * 64);
  const int r0 = tid >> 4, c4 = (tid & 15) * 4;
  f32x4 acc[RF][CF];
#pragma unroll
  for (int r = 0; r < RF; ++r)
#pragma unroll
    for (int c = 0; c < CF; ++c) acc[r][c] = (f32x4){0.f, 0.f, 0.f, 0.f};

  float4 pre[RF], pre2[RF];
#pragma unroll
  for (int it = 0; it < RF; ++it) {
    pre[it] = *(const float4*)(A + (rowbase + it * 16 + r0) * K + c4);
    if constexpr (SUM2)
      pre2[it] = *(const float4*)(A2 + (rowbase + it * 16 + r0) * K + c4);
  }

#pragma unroll
  for (int kc = 0; kc < K / 64; ++kc) {
    u16* As = (u16*)Asm[kc & 1];
#pragma unroll
    for (int it = 0; it < RF; ++it) {
      float4 v = pre[it];
      if constexpr (SUM2) {
        v.x += pre2[it].x; v.y += pre2[it].y;
        v.z += pre2[it].z; v.w += pre2[it].w;
      }
      ushort4 h;
      h.x = f2bf(v.x); h.y = f2bf(v.y); h.z = f2bf(v.z); h.w = f2bf(v.w);
      *(ushort4*)&As[(it * 16 + r0) * LD + c4] = h;
    }
    if (kc + 1 < K / 64) {
#pragma unroll
      for (int it = 0; it < RF; ++it) {
        pre[it] = *(const float4*)(A + (rowbase + it * 16 + r0) * K +
                                   (kc + 1) * 64 + c4);
        if constexpr (SUM2)
          pre2[it] = *(const float4*)(A2 + (rowbase + it * 16 + r0) * K +
                                      (kc + 1) * 64 + c4);
      }
    }
    barrier_lgkm();
#pragma unroll
    for (int s = 0; s < 2; ++s) {
      const int ko = s * 32 + q * 8;
      bf16x8 av[RF], bv[CF];
#pragma unroll
      for (int c = 0; c < CF; ++c)
        bv[c] = *(const bf16x8*)(Bt + (long)(colbase + wcol + c * 16 + m) * K +
                                 kc * 64 + ko);
#pragma unroll
      for (int r = 0; r < RF; ++r)
        av[r] = *(const bf16x8*)&As[(r * 16 + m) * LD + ko];
#pragma unroll
      for (int r = 0; r < RF; ++r)
#pragma unroll
        for (int c = 0; c < CF; ++c)
          acc[r][c] = __builtin_amdgcn_mfma_f32_16x16x32_bf16(
              av[r], bv[c], acc[r][c], 0, 0, 0);
    }
  }
#pragma unroll
  for (int r = 0; r < RF; ++r)
#pragma unroll
    for (int c = 0; c < CF; ++c)
#pragma unroll
      for (int g = 0; g < 4; ++g) {
        long gr = rowbase + r * 16 + q * 4 + g;
        long gc = colbase + wcol + c * 16 + m;
        float v = acc[r][c][g];
        if constexpr (OUT_BF16) ((u16*)Cv)[gr * Ntot + gc] = f2bf(v);
        else                    ((float*)Cv)[gr * Ntot + gc] = v;
        if constexpr (RELU0) {
          if (gc < 256) relu_dst[gr * 256 + gc] = fmaxf(v, 0.f);
        }
      }
}

// ---------------------------------------------------------------------------
// Weight tables (unchanged).
// ---------------------------------------------------------------------------
__global__ __launch_bounds__(256) void prep_bt(
    const float* __restrict__ weight, const float* __restrict__ align_lin,
    const float* __restrict__ fuse1_w, const float* __restrict__ fuse2_w,
    const float* __restrict__ fc1_w0, const float* __restrict__ fc2_w0,
    const float* __restrict__ fc3_w,
    u16* BtE1, u16* BtE2, u16* BtW0, u16* BtLoop, u16* BtFc3) {
  int g = blockIdx.x * 256 + threadIdx.x;  // 0..917503
  if (g < 262144) {
    int t = g & 131071;
    int col = t >> 8, k = t & 255;
    float v;
    if (g < 131072)
      v = (col < 256) ? fuse1_w[(256 + k) * 256 + col]
                      : fc1_w0[(512 + k) * 256 + (col - 256)];
    else
      v = (col < 256) ? fuse2_w[(256 + k) * 256 + col]
                      : fc2_w0[(512 + k) * 256 + (col - 256)];
    int ct = col >> 7, cc = col & 127, kc = k >> 6, kk = k & 63;
    u16* dst = (g < 131072) ? BtE1 : BtE2;
    dst[ct * 32768 + kc * 8192 + cc * 64 + (kk ^ ((cc & 7) * 8))] = f2bf(v);
  } else if (g < 393216) {
    int t = g - 262144;
    int c = t >> 8, k = t & 255;
    float v = (c < 256) ? weight[k * 256 + c] : align_lin[k * 256 + (c - 256)];
    BtW0[t] = f2bf(v);
  } else if (g < 786432) {
    int t = g - 393216;
    int c = t >> 8, k = t & 255;
    int seg = c >> 8, cc = c & 255;
    float v;
    if      (seg == 0) v = fuse1_w[k * 256 + cc];
    else if (seg == 1) v = fuse2_w[k * 256 + cc];
    else if (seg == 2) v = fc1_w0[k * 256 + cc];
    else if (seg == 3) v = fc1_w0[(256 + k) * 256 + cc];
    else if (seg == 4) v = fc2_w0[k * 256 + cc];
    else               v = fc2_w0[(256 + k) * 256 + cc];
    BtLoop[t] = f2bf(v);
  } else {
    int t = g - 786432;
    int c = t >> 9, k = t & 511;
    BtFc3[t] = f2bf(fc3_w[k * 256 + c]);
  }
}

// ---------------------------------------------------------------------------
// SelfAlignment (unchanged)
// ---------------------------------------------------------------------------
__global__ __launch_bounds__(128) void align_kernel(
    const float* __restrict__ text, const float* __restrict__ T0,
    const float* __restrict__ textmask, const float* __restrict__ align_bias,
    float* __restrict__ outss) {
  const int bi = blockIdx.x;
  const int b = bi >> 7;
  const int tid = threadIdx.x;
  __shared__ float ta[256];
  __shared__ float pr[128];
  __shared__ float red[128];
  ta[tid]       = T0[(long)bi * 512 + 256 + tid];
  ta[tid + 128] = T0[(long)bi * 512 + 384 + tid];
  __syncthreads();
  const float* trow = text + (long)(b * 128 + tid) * 256;
  float dot = 0.f;
  for (int d = 0; d < 256; d += 4) {
    float4 t4 = *(const float4*)(trow + d);
    dot += t4.x * ta[d] + t4.y * ta[d + 1] + t4.z * ta[d + 2] + t4.w * ta[d + 3];
  }
  float logit = dot + (1.0f - textmask[b * 128 + tid]) * -1e20f;
  pr[tid] = logit;
  red[tid] = logit;
  __syncthreads();
  for (int off = 64; off; off >>= 1) {
    if (tid < off) red[tid] = fmaxf(red[tid], red[tid + off]);
    __syncthreads();
  }
  float mx = red[0];
  __syncthreads();
  float e = __expf(pr[tid] - mx);
  red[tid] = e;
  __syncthreads();
  for (int off = 64; off; off >>= 1) {
    if (tid < off) red[tid] += red[tid + off];
    __syncthreads();
  }
  float inv = 1.0f / red[0];
  __syncthreads();
  pr[tid] = e * inv;
  __syncthreads();
  const float mi = textmask[bi];
  for (int h = 0; h < 2; ++h) {
    int d = tid + h * 128;
    float s = 0.f;
    for (int j = 0; j < 128; ++j)
      s += pr[j] * text[(long)(b * 128 + j) * 256 + d];
    outss[(long)bi * 256 + d] = s * mi + align_bias[d];
  }
}

// ---------------------------------------------------------------------------
// Fused gate/aggregate (unchanged): block = (b,i,half), 4 waves.
// ---------------------------------------------------------------------------
__global__ __launch_bounds__(256) void fused_gate(
    const u16* __restrict__ E1, const u16* __restrict__ E2,
    const float* __restrict__ P, const float* __restrict__ adj1,
    const float* __restrict__ adj2, const float* __restrict__ fc1w1,
    const float* __restrict__ fc1b1, const float* __restrict__ fc2w1,
    const float* __restrict__ fc2b1, float* __restrict__ OUa,
    float* __restrict__ OUb) {
  const int tid = threadIdx.x, lane = tid & 63, w = tid >> 6;
  const int bi = blockIdx.x >> 1, half = blockIdx.x & 1;
  const int b = bi >> 7;
  const int d4 = lane * 4;
  const long rowi = (long)bi * 1536;
  const long ebase = (long)bi * 65536;
  const int abase = bi * 128;
  float* __restrict__ OU = half ? OUb : OUa;

  __shared__ float sA[64], sB[64];
  __shared__ float redA[4][256], redB[4][256];
  __shared__ float dInv[2];

  if (tid < 64) sA[tid] = adj1[abase + half * 64 + tid];
  else if (tid < 128) sB[tid - 64] = adj2[abase + half * 64 + (tid - 64)];
  if (w == 0) {
    float v = adj1[abase + lane] + adj1[abase + 64 + lane];
#pragma unroll
    for (int off = 32; off; off >>= 1) v += __shfl_xor(v, off);
    if (lane == 0) dInv[0] = 1.f / (1.f + v);
  } else if (w == 1) {
    float v = adj2[abase + lane] + adj2[abase + 64 + lane];
#pragma unroll
    for (int off = 32; off; off >>= 1) v += __shfl_xor(v, off);
    if (lane == 0) dInv[1] = 1.f / (1.f + v);
  }
  __syncthreads();

  const float4 ti1 = *(const float4*)(P + rowi + 512 + d4);
  const float4 ti2 = *(const float4*)(P + rowi + 1024 + d4);
  const float4 w1v = *(const float4*)(fc1w1 + d4);
  const float4 w2v = *(const float4*)(fc2w1 + d4);
  const float b1 = fc1b1[0], b2 = fc2b1[0];

  float4 acc1 = {0.f, 0.f, 0.f, 0.f}, acc2 = {0.f, 0.f, 0.f, 0.f};

#pragma unroll 2
  for (int t = 0; t < 16; ++t) {
    const int jl = w * 16 + t;
    const int j = half * 64 + jl;
    const long er = ebase + (long)j * 512;
    const long rowj = (long)((b << 7) + j) * 1536;
    float4 e1c = unpack4(E1 + er + 256 + d4);
    float4 e2c = unpack4(E2 + er + 256 + d4);
    float4 t1 = *(const float4*)(P + rowj + 768 + d4);
    float4 t2 = *(const float4*)(P + rowj + 1280 + d4);
    float z1 = fmaxf(ti1.x + t1.x + e1c.x, 0.f) * w1v.x +
               fmaxf(ti1.y + t1.y + e1c.y, 0.f) * w1v.y +
               fmaxf(ti1.z + t1.z + e1c.z, 0.f) * w1v.z +
               fmaxf(ti1.w + t1.w + e1c.w, 0.f) * w1v.w;
    float z2 = fmaxf(ti2.x + t2.x + e2c.x, 0.f) * w2v.x +
               fmaxf(ti2.y + t2.y + e2c.y, 0.f) * w2v.y +
               fmaxf(ti2.z + t2.z + e2c.z, 0.f) * w2v.z +
               fmaxf(ti2.w + t2.w + e2c.w, 0.f) * w2v.w;
#pragma unroll
    for (int off = 1; off < 64; off <<= 1) {
      z1 += __shfl_xor(z1, off);
      z2 += __shfl_xor(z2, off);
    }
    float s1 = sA[jl] * __builtin_amdgcn_rcpf(1.f + __expf(-(z1 + b1)));
    float s2 = sB[jl] * __builtin_amdgcn_rcpf(1.f + __expf(-(z2 + b2)));
    float4 e1f = unpack4(E1 + er + d4);
    float4 e2f = unpack4(E2 + er + d4);
    float4 o1 = *(const float4*)(P + rowj + d4);
    float4 o2 = *(const float4*)(P + rowj + 256 + d4);
    acc1.x += s1 * fmaxf(o1.x + e1f.x, 0.f);
    acc1.y += s1 * fmaxf(o1.y + e1f.y, 0.f);
    acc1.z += s1 * fmaxf(o1.z + e1f.z, 0.f);
    acc1.w += s1 * fmaxf(o1.w + e1f.w, 0.f);
    acc2.x += s2 * fmaxf(o2.x + e2f.x, 0.f);
    acc2.y += s2 * fmaxf(o2.y + e2f.y, 0.f);
    acc2.z += s2 * fmaxf(o2.z + e2f.z, 0.f);
    acc2.w += s2 * fmaxf(o2.w + e2f.w, 0.f);
  }

  *(float4*)&redA[w][d4] = acc1;
  *(float4*)&redB[w][d4] = acc2;
  __syncthreads();
  float r1 = redA[0][tid] + redA[1][tid] + redA[2][tid] + redA[3][tid];
  float r2 = redB[0][tid] + redB[1][tid] + redB[2][tid] + redB[3][tid];
  OU[(long)bi * 512 + tid] = r1 * dInv[0];
  OU[(long)bi * 512 + 256 + tid] = r2 * dInv[1];
}

// ---------------------------------------------------------------------------
// out = layernorm(relu(Y) + prev + bias) * gamma + beta
// ---------------------------------------------------------------------------
__global__ __launch_bounds__(256) void ln_kernel(
    const float* __restrict__ Y, const float* __restrict__ prev,
    const float* __restrict__ bias, const float* __restrict__ gamma,
    const float* __restrict__ beta, float* __restrict__ dst) {
  const int row = blockIdx.x, tid = threadIdx.x, lane = tid & 63, w = tid >> 6;
  const long idx = (long)row * 256 + tid;
  float v = fmaxf(Y[idx], 0.f) + prev[idx] + bias[tid];
  float s = v;
#pragma unroll
  for (int off = 32; off; off >>= 1) s += __shfl_xor(s, off);
  __shared__ float wsA[4], wsB[4];
  if (lane == 0) wsA[w] = s;
  __syncthreads();
  float mean = (wsA[0] + wsA[1] + wsA[2] + wsA[3]) * (1.0f / 256.0f);
  float c = v - mean;
  float s2 = c * c;
#pragma unroll
  for (int off = 32; off; off >>= 1) s2 += __shfl_xor(s2, off);
  if (lane == 0) wsB[w] = s2;
  __syncthreads();
  float var = (wsB[0] + wsB[1] + wsB[2] + wsB[3]) * (1.0f / 256.0f);
  dst[idx] = c * rsqrtf(var + 1e-5f) * gamma[tid] + beta[tid];
}

// ---------------------------------------------------------------------------
extern "C" void kernel_launch(void* const* d_in, const int* in_sizes, int n_in,
                              void* d_out, int out_size, void* d_ws, size_t ws_size,
                              hipStream_t stream) {
  const float* text      = (const float*)d_in[0];
  const float* adj1      = (const float*)d_in[1];
  const float* adj2      = (const float*)d_in[2];
  const float* edge1     = (const float*)d_in[3];
  const float* edge2     = (const float*)d_in[4];
  const float* textmask  = (const float*)d_in[5];
  const float* weight    = (const float*)d_in[6];
  const float* bias      = (const float*)d_in[7];
  const float* gamma     = (const float*)d_in[8];
  const float* beta      = (const float*)d_in[9];
  const float* fuse1_w   = (const float*)d_in[10];
  const float* fuse2_w   = (const float*)d_in[11];
  const float* fc3_w     = (const float*)d_in[12];
  const float* fc1_w0    = (const float*)d_in[13];
  const float* fc1_w1    = (const float*)d_in[14];
  const float* fc1_b1    = (const float*)d_in[15];
  const float* fc2_w0    = (const float*)d_in[16];
  const float* fc2_w1    = (const float*)d_in[17];
  const float* fc2_b1    = (const float*)d_in[18];
  const float* align_lin = (const float*)d_in[19];
  const float* align_bias= (const float*)d_in[20];
  float* outF = (float*)d_out;  // out: [0,262144), outss: [262144,524288)

  char* w8 = (char*)d_ws;
  u16* E1   = (u16*)(w8 + 67108864);          // 128 MB
  u16* E2   = (u16*)(w8 + 201326592);         // 128 MB
  u16* BtE1 = (u16*)(w8 + 335544320);
  u16* BtE2 = BtE1 + 131072;
  u16* BtW0 = BtE2 + 131072;
  u16* BtLoop = BtW0 + 131072;                // 1536 x 256
  u16* BtFc3  = BtLoop + 393216;              // 256 x 512
  // small f32 buffers live in the first 64 MB
  float* P    = (float*)w8;                   // 1024 x 1536
  float* T0   = P + 1572864;                  // 1024 x 512
  float* OUa  = T0 + 524288;                  // 1024 x 512 (j-half 0 partial)
  float* OUb  = OUa + 524288;                 // 1024 x 512 (j-half 1 partial)
  float* outb = OUb + 524288;                 // 1024 x 256
  float* Yb   = outb + 262144;                // 1024 x 256

  // 1) weight tables
  prep_bt<<<3584, 256, 0, stream>>>(weight, align_lin, fuse1_w, fuse2_w,
                                    fc1_w0, fc2_w0, fc3_w,
                                    BtE1, BtE2, BtW0, BtLoop, BtFc3);
  // 2) edge projections: persistent blocks, 1 per CU
  gemm_edge<<<256, 512, 0, stream>>>(edge1, BtE1, E1);
  gemm_edge<<<256, 512, 0, stream>>>(edge2, BtE2, E2);
  // 3) T0 = text @ [weight | align_lin], relu of first 256 cols -> outb
  gemm_mfma<256, 2, 2, false, true, false><<<dim3(32, 4), 256, 0, stream>>>(
      text, BtW0, T0, 512, outb, nullptr);
  // 4) self-alignment -> outss
  align_kernel<<<1024, 128, 0, stream>>>(text, T0, textmask, align_bias,
                                         outF + 262144);
  // 5) K = 3 GCN iterations
  for (int it = 0; it < 3; ++it) {
    gemm_mfma<256, 2, 2, false, false, false><<<dim3(32, 12), 256, 0, stream>>>(
        outb, BtLoop, P, 1536, nullptr, nullptr);
    fused_gate<<<2048, 256, 0, stream>>>(E1, E2, P, adj1, adj2, fc1_w1, fc1_b1,
                                         fc2_w1, fc2_b1, OUa, OUb);
    gemm_mfma<512, 1, 2, false, false, true><<<dim3(64, 2), 256, 0, stream>>>(
        OUa, BtFc3, Yb, 256, nullptr, OUb);
    ln_kernel<<<1024, 256, 0, stream>>>(Yb, outb, bias, gamma, beta,
                                        (it == 2) ? outF : outb);
  }
}

// Round 5
// 706.208 us; speedup vs baseline: 1.1943x; 1.0098x over previous
//
#include <hip/hip_runtime.h>

typedef unsigned short u16;
typedef unsigned int u32;
typedef __attribute__((ext_vector_type(8))) short bf16x8;
typedef __attribute__((ext_vector_type(4))) float f32x4;

__device__ __forceinline__ u16 f2bf(float f) {
  u32 u = __float_as_uint(f);
  return (u16)((u + 0x7fffu + ((u >> 16) & 1u)) >> 16);
}

// unpack 4 bf16 -> 4 f32 (one 8-B load)
__device__ __forceinline__ float4 unpack4(const u16* p) {
  uint2 a = *(const uint2*)p;
  float4 r;
  r.x = __uint_as_float(a.x << 16);
  r.y = __uint_as_float(a.x & 0xffff0000u);
  r.z = __uint_as_float(a.y << 16);
  r.w = __uint_as_float(a.y & 0xffff0000u);
  return r;
}

__device__ __forceinline__ void glds16(const void* g, void* l) {
  __builtin_amdgcn_global_load_lds(
      (const __attribute__((address_space(1))) unsigned int*)g,
      (__attribute__((address_space(3))) unsigned int*)l, 16, 0, 0);
}

// lgkm-only barrier: does NOT drain vmcnt, so global prefetches stay in
// flight across it.
__device__ __forceinline__ void barrier_lgkm() {
  asm volatile("s_waitcnt lgkmcnt(0)" ::: "memory");
  __builtin_amdgcn_s_barrier();
  asm volatile("" ::: "memory");
}
// plain barrier (no waitcnt): used where reads are already drained per-wave
__device__ __forceinline__ void barrier_plain() {
  asm volatile("" ::: "memory");
  __builtin_amdgcn_s_barrier();
  asm volatile("" ::: "memory");
}

// ---------------------------------------------------------------------------
// Edge GEMM v5: E[131072 x 512] = edge(f32) @ Bt(bf16)^T, K=256.
// 512 blocks x 256 thr (2 blocks/CU for cross-block pipe overlap).
// Block owns a 128-col strip (cs) and 8 rt tiles (rg). B strip (64 KB,
// tiled+swizzled) loaded to LDS ONCE. A tile 128x64 single-buffered:
// plain barrier -> packed conflict-free b128 swizzled writes -> issue
// next-step A prefetch -> lgkm barrier -> ds_read + MFMA (waves 64x64,
// 16 reads / 32 MFMA). LDS/block = 80 KB.
// ---------------------------------------------------------------------------
__global__ __launch_bounds__(256) void gemm_edge(
    const float* __restrict__ Af, const u16* __restrict__ Bt,
    u16* __restrict__ E) {
  __shared__ __align__(16) u16 Bsm[32768];  // 64 KB B strip [4kc][128c][64k]
  __shared__ __align__(16) u16 Asm[8192];   // 16 KB A tile 128x64
  const int tid = threadIdx.x, lane = tid & 63, w = tid >> 6;
  const int m = lane & 15, q = lane >> 4;
  const int b = blockIdx.x;
  const int x = b & 7, v = b >> 3;          // XCD x; index within XCD
  const int cs = v & 3;                     // col strip (128 cols)
  const int rg = x * 16 + (v >> 2);         // row group: 8 rt tiles
  const int wrow = (w & 1) * 64, wcol = (w >> 1) * 64;
  const char* Bb = (const char*)Bt + (long)cs * 65536;

  // B -> LDS once (linear copy preserves tiled+swizzled layout)
#pragma unroll
  for (int i = 0; i < 16; ++i)
    glds16(Bb + i * 4096 + tid * 16, (char*)Bsm + i * 4096 + tid * 16);
  __syncthreads();  // one full drain: B resident before loop

  const int sr = w * 32 + (lane >> 3);   // this lane stages rows sr + i*8
  const int sc = (lane & 7) * 8;         // float col base within 64-wide kc
  const int slot = (lane & 7) * 16;      // byte chunk (pre-XOR)

  const float* Ab0 = Af + (long)rg * 8 * 32768;
  float4 pa[4], pb[4];
#pragma unroll
  for (int i = 0; i < 4; ++i) {
    const float* src = Ab0 + (long)(sr + i * 8) * 256 + sc;
    pa[i] = *(const float4*)src;
    pb[i] = *(const float4*)(src + 4);
  }

  f32x4 acc[4][4];
  for (int t = 0; t < 8; ++t) {
    const float* Ab = Ab0 + (long)t * 32768;
#pragma unroll
    for (int r = 0; r < 4; ++r)
#pragma unroll
      for (int c = 0; c < 4; ++c) acc[r][c] = (f32x4){0.f, 0.f, 0.f, 0.f};
#pragma unroll
    for (int kc = 0; kc < 4; ++kc) {
      // all waves' reads of the previous step are complete (drained pre-MFMA)
      barrier_plain();
      // packed, conflict-free, swizzled A write (b128 per lane per 8-row grp)
#pragma unroll
      for (int i = 0; i < 4; ++i) {
        int row = sr + i * 8;
        uint4 st;
        st.x = (u32)f2bf(pa[i].x) | ((u32)f2bf(pa[i].y) << 16);
        st.y = (u32)f2bf(pa[i].z) | ((u32)f2bf(pa[i].w) << 16);
        st.z = (u32)f2bf(pb[i].x) | ((u32)f2bf(pb[i].y) << 16);
        st.w = (u32)f2bf(pb[i].z) | ((u32)f2bf(pb[i].w) << 16);
        *(uint4*)((char*)Asm + row * 128 + (slot ^ ((row & 7) * 16))) = st;
      }
      // issue next-step A prefetch (hides under MFMA below)
      if (kc < 3 || t < 7) {
        const int kc2 = (kc + 1) & 3;
        const float* An = (kc < 3) ? Ab : (Ab + 32768);
#pragma unroll
        for (int i = 0; i < 4; ++i) {
          const float* src = An + (long)(sr + i * 8) * 256 + kc2 * 64 + sc;
          pa[i] = *(const float4*)src;
          pb[i] = *(const float4*)(src + 4);
        }
      }
      barrier_lgkm();
      // MFMA: wave 64x64, 16 ds_read_b128 feed 32 MFMAs
#pragma unroll
      for (int s = 0; s < 2; ++s) {
        const int ko2 = (s * 32 + q * 8) * 2;
        bf16x8 av[4], bv[4];
#pragma unroll
        for (int r = 0; r < 4; ++r) {
          int row = wrow + r * 16 + m;
          av[r] = *(const bf16x8*)((char*)Asm + row * 128 +
                                   (ko2 ^ ((row & 7) * 16)));
        }
#pragma unroll
        for (int c = 0; c < 4; ++c) {
          int col = wcol + c * 16 + m;
          bv[c] = *(const bf16x8*)((char*)Bsm + kc * 16384 + col * 128 +
                                   (ko2 ^ ((col & 7) * 16)));
        }
#pragma unroll
        for (int r = 0; r < 4; ++r)
#pragma unroll
          for (int c = 0; c < 4; ++c)
            acc[r][c] = __builtin_amdgcn_mfma_f32_16x16x32_bf16(
                av[r], bv[c], acc[r][c], 0, 0, 0);
      }
    }
    // epilogue: store E tile (t+1 prefetch already in flight)
    const long grow = (long)(rg * 8 + t) * 128;
#pragma unroll
    for (int r = 0; r < 4; ++r)
#pragma unroll
      for (int c = 0; c < 4; ++c)
#pragma unroll
        for (int g = 0; g < 4; ++g) {
          long gr = grow + wrow + r * 16 + q * 4 + g;
          int gc = cs * 128 + wcol + c * 16 + m;
          E[gr * 512 + gc] = f2bf(acc[r][c][g]);
        }
  }
}

// ---------------------------------------------------------------------------
// Generic small GEMM: C[M x Ntot] = A[M x K](f32) * Bt[Ntot x K](bf16)^T.
// Tile = RF*16 rows x CF*64 cols, 4 waves. A dbuf LDS + reg prefetch;
// B direct from global (L2). RELU0: relu(cols<256) -> relu_dst. SUM2: A+=A2.
// ---------------------------------------------------------------------------
template<int K, int RF, int CF, bool OUT_BF16, bool RELU0, bool SUM2>
__global__ __launch_bounds__(256) void gemm_mfma(
    const float* __restrict__ A, const u16* __restrict__ Bt,
    void* __restrict__ Cv, int Ntot, float* __restrict__ relu_dst,
    const float* __restrict__ A2) {
  constexpr int ROWS = RF * 16;
  constexpr int LD = 72;
  __shared__ __align__(16) u16 Asm[2][ROWS * LD];
  const int tid = threadIdx.x;
  const int lane = tid & 63;
  const int w = tid >> 6;
  const int m = lane & 15;
  const int q = lane >> 4;
  const int wcol = w * (CF * 16);
  const long rowbase = (long)blockIdx.x * ROWS;
  const long colbase = (long)blockIdx.y * (CF * 64);
  const int r0 = tid >> 4, c4 = (tid & 15) * 4;
  f32x4 acc[RF][CF];
#pragma unroll
  for (int r = 0; r < RF; ++r)
#pragma unroll
    for (int c = 0; c < CF; ++c) acc[r][c] = (f32x4){0.f, 0.f, 0.f, 0.f};

  float4 pre[RF], pre2[RF];
#pragma unroll
  for (int it = 0; it < RF; ++it) {
    pre[it] = *(const float4*)(A + (rowbase + it * 16 + r0) * K + c4);
    if constexpr (SUM2)
      pre2[it] = *(const float4*)(A2 + (rowbase + it * 16 + r0) * K + c4);
  }

#pragma unroll
  for (int kc = 0; kc < K / 64; ++kc) {
    u16* As = (u16*)Asm[kc & 1];
#pragma unroll
    for (int it = 0; it < RF; ++it) {
      float4 v = pre[it];
      if constexpr (SUM2) {
        v.x += pre2[it].x; v.y += pre2[it].y;
        v.z += pre2[it].z; v.w += pre2[it].w;
      }
      ushort4 h;
      h.x = f2bf(v.x); h.y = f2bf(v.y); h.z = f2bf(v.z); h.w = f2bf(v.w);
      *(ushort4*)&As[(it * 16 + r0) * LD + c4] = h;
    }
    if (kc + 1 < K / 64) {
#pragma unroll
      for (int it = 0; it < RF; ++it) {
        pre[it] = *(const float4*)(A + (rowbase + it * 16 + r0) * K +
                                   (kc + 1) * 64 + c4);
        if constexpr (SUM2)
          pre2[it] = *(const float4*)(A2 + (rowbase + it * 16 + r0) * K +
                                      (kc + 1) * 64 + c4);
      }
    }
    barrier_lgkm();
#pragma unroll
    for (int s = 0; s < 2; ++s) {
      const int ko = s * 32 + q * 8;
      bf16x8 av[RF], bv[CF];
#pragma unroll
      for (int c = 0; c < CF; ++c)
        bv[c] = *(const bf16x8*)(Bt + (long)(colbase + wcol + c * 16 + m) * K +
                                 kc * 64 + ko);
#pragma unroll
      for (int r = 0; r < RF; ++r)
        av[r] = *(const bf16x8*)&As[(r * 16 + m) * LD + ko];
#pragma unroll
      for (int r = 0; r < RF; ++r)
#pragma unroll
        for (int c = 0; c < CF; ++c)
          acc[r][c] = __builtin_amdgcn_mfma_f32_16x16x32_bf16(
              av[r], bv[c], acc[r][c], 0, 0, 0);
    }
  }
#pragma unroll
  for (int r = 0; r < RF; ++r)
#pragma unroll
    for (int c = 0; c < CF; ++c)
#pragma unroll
      for (int g = 0; g < 4; ++g) {
        long gr = rowbase + r * 16 + q * 4 + g;
        long gc = colbase + wcol + c * 16 + m;
        float v = acc[r][c][g];
        if constexpr (OUT_BF16) ((u16*)Cv)[gr * Ntot + gc] = f2bf(v);
        else                    ((float*)Cv)[gr * Ntot + gc] = v;
        if constexpr (RELU0) {
          if (gc < 256) relu_dst[gr * 256 + gc] = fmaxf(v, 0.f);
        }
      }
}

// ---------------------------------------------------------------------------
// Weight tables (unchanged).
// ---------------------------------------------------------------------------
__global__ __launch_bounds__(256) void prep_bt(
    const float* __restrict__ weight, const float* __restrict__ align_lin,
    const float* __restrict__ fuse1_w, const float* __restrict__ fuse2_w,
    const float* __restrict__ fc1_w0, const float* __restrict__ fc2_w0,
    const float* __restrict__ fc3_w,
    u16* BtE1, u16* BtE2, u16* BtW0, u16* BtLoop, u16* BtFc3) {
  int g = blockIdx.x * 256 + threadIdx.x;  // 0..917503
  if (g < 262144) {
    int t = g & 131071;
    int col = t >> 8, k = t & 255;
    float v;
    if (g < 131072)
      v = (col < 256) ? fuse1_w[(256 + k) * 256 + col]
                      : fc1_w0[(512 + k) * 256 + (col - 256)];
    else
      v = (col < 256) ? fuse2_w[(256 + k) * 256 + col]
                      : fc2_w0[(512 + k) * 256 + (col - 256)];
    int ct = col >> 7, cc = col & 127, kc = k >> 6, kk = k & 63;
    u16* dst = (g < 131072) ? BtE1 : BtE2;
    dst[ct * 32768 + kc * 8192 + cc * 64 + (kk ^ ((cc & 7) * 8))] = f2bf(v);
  } else if (g < 393216) {
    int t = g - 262144;
    int c = t >> 8, k = t & 255;
    float v = (c < 256) ? weight[k * 256 + c] : align_lin[k * 256 + (c - 256)];
    BtW0[t] = f2bf(v);
  } else if (g < 786432) {
    int t = g - 393216;
    int c = t >> 8, k = t & 255;
    int seg = c >> 8, cc = c & 255;
    float v;
    if      (seg == 0) v = fuse1_w[k * 256 + cc];
    else if (seg == 1) v = fuse2_w[k * 256 + cc];
    else if (seg == 2) v = fc1_w0[k * 256 + cc];
    else if (seg == 3) v = fc1_w0[(256 + k) * 256 + cc];
    else if (seg == 4) v = fc2_w0[k * 256 + cc];
    else               v = fc2_w0[(256 + k) * 256 + cc];
    BtLoop[t] = f2bf(v);
  } else {
    int t = g - 786432;
    int c = t >> 9, k = t & 511;
    BtFc3[t] = f2bf(fc3_w[k * 256 + c]);
  }
}

// ---------------------------------------------------------------------------
// SelfAlignment (unchanged)
// ---------------------------------------------------------------------------
__global__ __launch_bounds__(128) void align_kernel(
    const float* __restrict__ text, const float* __restrict__ T0,
    const float* __restrict__ textmask, const float* __restrict__ align_bias,
    float* __restrict__ outss) {
  const int bi = blockIdx.x;
  const int b = bi >> 7;
  const int tid = threadIdx.x;
  __shared__ float ta[256];
  __shared__ float pr[128];
  __shared__ float red[128];
  ta[tid]       = T0[(long)bi * 512 + 256 + tid];
  ta[tid + 128] = T0[(long)bi * 512 + 384 + tid];
  __syncthreads();
  const float* trow = text + (long)(b * 128 + tid) * 256;
  float dot = 0.f;
  for (int d = 0; d < 256; d += 4) {
    float4 t4 = *(const float4*)(trow + d);
    dot += t4.x * ta[d] + t4.y * ta[d + 1] + t4.z * ta[d + 2] + t4.w * ta[d + 3];
  }
  float logit = dot + (1.0f - textmask[b * 128 + tid]) * -1e20f;
  pr[tid] = logit;
  red[tid] = logit;
  __syncthreads();
  for (int off = 64; off; off >>= 1) {
    if (tid < off) red[tid] = fmaxf(red[tid], red[tid + off]);
    __syncthreads();
  }
  float mx = red[0];
  __syncthreads();
  float e = __expf(pr[tid] - mx);
  red[tid] = e;
  __syncthreads();
  for (int off = 64; off; off >>= 1) {
    if (tid < off) red[tid] += red[tid + off];
    __syncthreads();
  }
  float inv = 1.0f / red[0];
  __syncthreads();
  pr[tid] = e * inv;
  __syncthreads();
  const float mi = textmask[bi];
  for (int h = 0; h < 2; ++h) {
    int d = tid + h * 128;
    float s = 0.f;
    for (int j = 0; j < 128; ++j)
      s += pr[j] * text[(long)(b * 128 + j) * 256 + d];
    outss[(long)bi * 256 + d] = s * mi + align_bias[d];
  }
}

// ---------------------------------------------------------------------------
// Fused gate/aggregate (unchanged): block = (b,i,half), 4 waves.
// ---------------------------------------------------------------------------
__global__ __launch_bounds__(256) void fused_gate(
    const u16* __restrict__ E1, const u16* __restrict__ E2,
    const float* __restrict__ P, const float* __restrict__ adj1,
    const float* __restrict__ adj2, const float* __restrict__ fc1w1,
    const float* __restrict__ fc1b1, const float* __restrict__ fc2w1,
    const float* __restrict__ fc2b1, float* __restrict__ OUa,
    float* __restrict__ OUb) {
  const int tid = threadIdx.x, lane = tid & 63, w = tid >> 6;
  const int bi = blockIdx.x >> 1, half = blockIdx.x & 1;
  const int b = bi >> 7;
  const int d4 = lane * 4;
  const long rowi = (long)bi * 1536;
  const long ebase = (long)bi * 65536;
  const int abase = bi * 128;
  float* __restrict__ OU = half ? OUb : OUa;

  __shared__ float sA[64], sB[64];
  __shared__ float redA[4][256], redB[4][256];
  __shared__ float dInv[2];

  if (tid < 64) sA[tid] = adj1[abase + half * 64 + tid];
  else if (tid < 128) sB[tid - 64] = adj2[abase + half * 64 + (tid - 64)];
  if (w == 0) {
    float v = adj1[abase + lane] + adj1[abase + 64 + lane];
#pragma unroll
    for (int off = 32; off; off >>= 1) v += __shfl_xor(v, off);
    if (lane == 0) dInv[0] = 1.f / (1.f + v);
  } else if (w == 1) {
    float v = adj2[abase + lane] + adj2[abase + 64 + lane];
#pragma unroll
    for (int off = 32; off; off >>= 1) v += __shfl_xor(v, off);
    if (lane == 0) dInv[1] = 1.f / (1.f + v);
  }
  __syncthreads();

  const float4 ti1 = *(const float4*)(P + rowi + 512 + d4);
  const float4 ti2 = *(const float4*)(P + rowi + 1024 + d4);
  const float4 w1v = *(const float4*)(fc1w1 + d4);
  const float4 w2v = *(const float4*)(fc2w1 + d4);
  const float b1 = fc1b1[0], b2 = fc2b1[0];

  float4 acc1 = {0.f, 0.f, 0.f, 0.f}, acc2 = {0.f, 0.f, 0.f, 0.f};

#pragma unroll 2
  for (int t = 0; t < 16; ++t) {
    const int jl = w * 16 + t;
    const int j = half * 64 + jl;
    const long er = ebase + (long)j * 512;
    const long rowj = (long)((b << 7) + j) * 1536;
    float4 e1c = unpack4(E1 + er + 256 + d4);
    float4 e2c = unpack4(E2 + er + 256 + d4);
    float4 t1 = *(const float4*)(P + rowj + 768 + d4);
    float4 t2 = *(const float4*)(P + rowj + 1280 + d4);
    float z1 = fmaxf(ti1.x + t1.x + e1c.x, 0.f) * w1v.x +
               fmaxf(ti1.y + t1.y + e1c.y, 0.f) * w1v.y +
               fmaxf(ti1.z + t1.z + e1c.z, 0.f) * w1v.z +
               fmaxf(ti1.w + t1.w + e1c.w, 0.f) * w1v.w;
    float z2 = fmaxf(ti2.x + t2.x + e2c.x, 0.f) * w2v.x +
               fmaxf(ti2.y + t2.y + e2c.y, 0.f) * w2v.y +
               fmaxf(ti2.z + t2.z + e2c.z, 0.f) * w2v.z +
               fmaxf(ti2.w + t2.w + e2c.w, 0.f) * w2v.w;
#pragma unroll
    for (int off = 1; off < 64; off <<= 1) {
      z1 += __shfl_xor(z1, off);
      z2 += __shfl_xor(z2, off);
    }
    float s1 = sA[jl] * __builtin_amdgcn_rcpf(1.f + __expf(-(z1 + b1)));
    float s2 = sB[jl] * __builtin_amdgcn_rcpf(1.f + __expf(-(z2 + b2)));
    float4 e1f = unpack4(E1 + er + d4);
    float4 e2f = unpack4(E2 + er + d4);
    float4 o1 = *(const float4*)(P + rowj + d4);
    float4 o2 = *(const float4*)(P + rowj + 256 + d4);
    acc1.x += s1 * fmaxf(o1.x + e1f.x, 0.f);
    acc1.y += s1 * fmaxf(o1.y + e1f.y, 0.f);
    acc1.z += s1 * fmaxf(o1.z + e1f.z, 0.f);
    acc1.w += s1 * fmaxf(o1.w + e1f.w, 0.f);
    acc2.x += s2 * fmaxf(o2.x + e2f.x, 0.f);
    acc2.y += s2 * fmaxf(o2.y + e2f.y, 0.f);
    acc2.z += s2 * fmaxf(o2.z + e2f.z, 0.f);
    acc2.w += s2 * fmaxf(o2.w + e2f.w, 0.f);
  }

  *(float4*)&redA[w][d4] = acc1;
  *(float4*)&redB[w][d4] = acc2;
  __syncthreads();
  float r1 = redA[0][tid] + redA[1][tid] + redA[2][tid] + redA[3][tid];
  float r2 = redB[0][tid] + redB[1][tid] + redB[2][tid] + redB[3][tid];
  OU[(long)bi * 512 + tid] = r1 * dInv[0];
  OU[(long)bi * 512 + 256 + tid] = r2 * dInv[1];
}

// ---------------------------------------------------------------------------
// out = layernorm(relu(Y) + prev + bias) * gamma + beta
// ---------------------------------------------------------------------------
__global__ __launch_bounds__(256) void ln_kernel(
    const float* __restrict__ Y, const float* __restrict__ prev,
    const float* __restrict__ bias, const float* __restrict__ gamma,
    const float* __restrict__ beta, float* __restrict__ dst) {
  const int row = blockIdx.x, tid = threadIdx.x, lane = tid & 63, w = tid >> 6;
  const long idx = (long)row * 256 + tid;
  float v = fmaxf(Y[idx], 0.f) + prev[idx] + bias[tid];
  float s = v;
#pragma unroll
  for (int off = 32; off; off >>= 1) s += __shfl_xor(s, off);
  __shared__ float wsA[4], wsB[4];
  if (lane == 0) wsA[w] = s;
  __syncthreads();
  float mean = (wsA[0] + wsA[1] + wsA[2] + wsA[3]) * (1.0f / 256.0f);
  float c = v - mean;
  float s2 = c * c;
#pragma unroll
  for (int off = 32; off; off >>= 1) s2 += __shfl_xor(s2, off);
  if (lane == 0) wsB[w] = s2;
  __syncthreads();
  float var = (wsB[0] + wsB[1] + wsB[2] + wsB[3]) * (1.0f / 256.0f);
  dst[idx] = c * rsqrtf(var + 1e-5f) * gamma[tid] + beta[tid];
}

// ---------------------------------------------------------------------------
extern "C" void kernel_launch(void* const* d_in, const int* in_sizes, int n_in,
                              void* d_out, int out_size, void* d_ws, size_t ws_size,
                              hipStream_t stream) {
  const float* text      = (const float*)d_in[0];
  const float* adj1      = (const float*)d_in[1];
  const float* adj2      = (const float*)d_in[2];
  const float* edge1     = (const float*)d_in[3];
  const float* edge2     = (const float*)d_in[4];
  const float* textmask  = (const float*)d_in[5];
  const float* weight    = (const float*)d_in[6];
  const float* bias      = (const float*)d_in[7];
  const float* gamma     = (const float*)d_in[8];
  const float* beta      = (const float*)d_in[9];
  const float* fuse1_w   = (const float*)d_in[10];
  const float* fuse2_w   = (const float*)d_in[11];
  const float* fc3_w     = (const float*)d_in[12];
  const float* fc1_w0    = (const float*)d_in[13];
  const float* fc1_w1    = (const float*)d_in[14];
  const float* fc1_b1    = (const float*)d_in[15];
  const float* fc2_w0    = (const float*)d_in[16];
  const float* fc2_w1    = (const float*)d_in[17];
  const float* fc2_b1    = (const float*)d_in[18];
  const float* align_lin = (const float*)d_in[19];
  const float* align_bias= (const float*)d_in[20];
  float* outF = (float*)d_out;  // out: [0,262144), outss: [262144,524288)

  char* w8 = (char*)d_ws;
  u16* E1   = (u16*)(w8 + 67108864);          // 128 MB
  u16* E2   = (u16*)(w8 + 201326592);         // 128 MB
  u16* BtE1 = (u16*)(w8 + 335544320);
  u16* BtE2 = BtE1 + 131072;
  u16* BtW0 = BtE2 + 131072;
  u16* BtLoop = BtW0 + 131072;                // 1536 x 256
  u16* BtFc3  = BtLoop + 393216;              // 256 x 512
  // small f32 buffers live in the first 64 MB
  float* P    = (float*)w8;                   // 1024 x 1536
  float* T0   = P + 1572864;                  // 1024 x 512
  float* OUa  = T0 + 524288;                  // 1024 x 512 (j-half 0 partial)
  float* OUb  = OUa + 524288;                 // 1024 x 512 (j-half 1 partial)
  float* outb = OUb + 524288;                 // 1024 x 256
  float* Yb   = outb + 262144;                // 1024 x 256

  // 1) weight tables
  prep_bt<<<3584, 256, 0, stream>>>(weight, align_lin, fuse1_w, fuse2_w,
                                    fc1_w0, fc2_w0, fc3_w,
                                    BtE1, BtE2, BtW0, BtLoop, BtFc3);
  // 2) edge projections: 512 blocks, 2 per CU
  gemm_edge<<<512, 256, 0, stream>>>(edge1, BtE1, E1);
  gemm_edge<<<512, 256, 0, stream>>>(edge2, BtE2, E2);
  // 3) T0 = text @ [weight | align_lin], relu of first 256 cols -> outb
  gemm_mfma<256, 2, 2, false, true, false><<<dim3(32, 4), 256, 0, stream>>>(
      text, BtW0, T0, 512, outb, nullptr);
  // 4) self-alignment -> outss
  align_kernel<<<1024, 128, 0, stream>>>(text, T0, textmask, align_bias,
                                         outF + 262144);
  // 5) K = 3 GCN iterations
  for (int it = 0; it < 3; ++it) {
    gemm_mfma<256, 2, 2, false, false, false><<<dim3(32, 12), 256, 0, stream>>>(
        outb, BtLoop, P, 1536, nullptr, nullptr);
    fused_gate<<<2048, 256, 0, stream>>>(E1, E2, P, adj1, adj2, fc1_w1, fc1_b1,
                                         fc2_w1, fc2_b1, OUa, OUb);
    gemm_mfma<512, 1, 2, false, false, true><<<dim3(64, 2), 256, 0, stream>>>(
        OUa, BtFc3, Yb, 256, nullptr, OUb);
    ln_kernel<<<1024, 256, 0, stream>>>(Yb, outb, bias, gamma, beta,
                                        (it == 2) ? outF : outb);
  }
}